// Round 13
// baseline (907.786 us; speedup 1.0000x reference)
//
#include <hip/hip_runtime.h>
#include <hip/hip_bf16.h>
#include <hip/hip_fp16.h>

#define NN 40000
#define NE 640000
#define HD 128
#define DEPTH 4
#define NG 1250
#define TD 32
#define AFN 9
#define AVN 64
#define BFN 3
#define BVN 8
#define NBLK2 (NE / 128)   // 5000, divisible by 8

typedef short bf16x8 __attribute__((ext_vector_type(8)));
typedef _Float16 f16x8 __attribute__((ext_vector_type(8)));
typedef _Float16 f16x2 __attribute__((ext_vector_type(2)));
typedef float f32x4 __attribute__((ext_vector_type(4)));

__device__ __forceinline__ uint cvtpk(float lo, float hi){
  uint r; asm("v_cvt_pk_bf16_f32 %0, %1, %2" : "=v"(r) : "v"(lo), "v"(hi)); return r;
}
__device__ __forceinline__ ushort f2bf(float x){ return (ushort)cvtpk(x, x); }
__device__ __forceinline__ float rcpfa(float x){ return __builtin_amdgcn_rcpf(x); }
__device__ __forceinline__ float siluf(float x){ return x * rcpfa(1.f + __expf(-x)); }
__device__ __forceinline__ float sigmf(float x){ return rcpfa(1.f + __expf(-x)); }
__device__ __forceinline__ uint packbf2(float a, float b){ return cvtpk(a, b); }

__device__ __forceinline__ __half2 silu_h2(__half2 x){
  const __half2 nl2e = __float2half2_rn(-1.44269504f);
  const __half2 one  = __float2half2_rn(1.f);
  __half2 e = h2exp2(__hmul2(x, nl2e));
  return __hmul2(x, h2rcp(__hadd2(one, e)));
}
union H2U { __half2 h; f16x2 v; uint u; };
__device__ __forceinline__ __half2 pkrtz(float lo, float hi){
  auto t = __builtin_amdgcn_cvt_pkrtz(lo, hi);
  H2U r; __builtin_memcpy(&r.u, &t, 4); return r.h;
}

// ---------------- pack all weights in one launch ----------------
__device__ __forceinline__ void pack_one(const float* __restrict__ src,
                                         ushort* __restrict__ dst,
                                         int K, int L, int isf16){
  int total = L * K * HD;
  for (int idx = blockIdx.x * blockDim.x + threadIdx.x; idx < total;
       idx += gridDim.x * blockDim.x){
    int l = idx / (K * HD);
    int r = idx - l * K * HD;
    int k = r / HD;
    int n = r - k * HD;
    float v = src[idx];
    ushort o;
    if (isf16){ __half hv = __float2half_rn(v); o = *(ushort*)&hv; }
    else o = f2bf(v);
    dst[(size_t)l * K * HD + ((size_t)(k >> 3) * HD + n) * 8 + (k & 7)] = o;
  }
}
__global__ void pack6(const float* s0, const float* s1, const float* s2,
                      const float* s3, const float* s4, const float* s5,
                      ushort* d0, ushort* d1, ushort* d2,
                      ushort* d3, ushort* d4, ushort* d5){
  switch (blockIdx.y){
    case 0: pack_one(s0, d0, 384, DEPTH, 0); break;
    case 1: pack_one(s1, d1, HD, DEPTH, 1); break;
    case 2: pack_one(s2, d2, HD, DEPTH, 0); break;
    case 3: pack_one(s3, d3, HD, DEPTH, 0); break;
    case 4: pack_one(s4, d4, HD, 1, 0); break;
    default: pack_one(s5, d5, HD, 1, 0); break;
  }
}

__global__ void zero_i(int* __restrict__ p, int n){
  for (int i = blockIdx.x * blockDim.x + threadIdx.x; i < n; i += gridDim.x * blockDim.x)
    p[i] = 0;
}

// ---------------- atom encoder ----------------
__global__ void atom_encode(const int* __restrict__ feat, const float* __restrict__ emb,
                            float* __restrict__ h, ushort* __restrict__ hbf){
  int n = blockIdx.x;
  int c = threadIdx.x; // 128
  float acc = 0.f;
#pragma unroll
  for (int f = 0; f < AFN; ++f){
    int v = feat[n * AFN + f];
    acc += emb[(size_t)(f * AVN + v) * HD + c];
  }
  h[(size_t)n * HD + c] = acc;
  hbf[(size_t)n * HD + c] = f2bf(acc);
}

// ---------------- bond combo table: ebf[512][128] bf16 ----------------
__global__ void ebf_k(const float* __restrict__ bemb, ushort* __restrict__ ebf){
  const int cid = blockIdx.x;      // 512
  const int c = threadIdx.x;       // 128
  const int f0 = cid >> 6, f1 = (cid >> 3) & 7, f2 = cid & 7;
  float v = bemb[(size_t)(0 * BVN + f0) * HD + c]
          + bemb[(size_t)(1 * BVN + f1) * HD + c]
          + bemb[(size_t)(2 * BVN + f2) * HD + c];
  ebf[(size_t)cid * HD + c] = f2bf(v);
}

// ---------------- edge histogram by dst ----------------
__global__ void hist_k(const int* __restrict__ edst, int* __restrict__ deg){
  for (int e = blockIdx.x * blockDim.x + threadIdx.x; e < NE; e += gridDim.x * blockDim.x)
    atomicAdd(&deg[edst[e]], 1);
}

// ---------------- exclusive scan over NN=40000 (single block, 1024 thr) ----------------
__global__ __launch_bounds__(1024) void scan_head(const int* __restrict__ deg,
                                                  int* __restrict__ head){
  __shared__ int buf[1024];
  const int t = threadIdx.x;
  const int base = t * 40;
  int s = 0;
  int dloc[40];
  if (t < 1000){
#pragma unroll
    for (int i = 0; i < 40; ++i){ dloc[i] = deg[base + i]; s += dloc[i]; }
  }
  buf[t] = s;
  __syncthreads();
  for (int ofs = 1; ofs < 1024; ofs <<= 1){
    int x = (t >= ofs) ? buf[t - ofs] : 0;
    __syncthreads();
    buf[t] += x;
    __syncthreads();
  }
  if (t < 1000){
    int run = buf[t] - s;
#pragma unroll
    for (int i = 0; i < 40; ++i){ head[base + i] = run; run += dloc[i]; }
  }
}

// ---------------- scatter edges into dst-sorted order ----------------
__global__ void scatter_k(const int* __restrict__ esrc, const int* __restrict__ edst,
                          const int* __restrict__ bfeat, int* __restrict__ head,
                          int* __restrict__ esrc_p, int* __restrict__ dst_p,
                          int* __restrict__ cid_p){
  for (int e = blockIdx.x * blockDim.x + threadIdx.x; e < NE; e += gridDim.x * blockDim.x){
    const int d = edst[e];
    const int pos = atomicAdd(&head[d], 1);
    esrc_p[pos] = esrc[e];
    dst_p[pos] = d;
    cid_p[pos] = bfeat[e * 3 + 0] * 64 + bfeat[e * 3 + 1] * 8 + bfeat[e * 3 + 2];
  }
}

// ---------------- per-layer node precompute: prea/preb = hbf@W1a/b (f16) + zero msum ----------------
__global__ __launch_bounds__(256) void pre_k(
    const ushort* __restrict__ hbf, const ushort* __restrict__ W1p,
    __half* __restrict__ prea, __half* __restrict__ preb,
    uint* __restrict__ msum2)
{
  const int tid = threadIdx.x;
  const int n0 = blockIdx.x * 64;
  { // zero this block's msum2 rows (64 nodes x 64 pairs = 1024 uint4)
    uint4* mz = (uint4*)(msum2 + (size_t)n0 * 64);
    const uint4 z = make_uint4(0u, 0u, 0u, 0u);
#pragma unroll
    for (int i = 0; i < 4; ++i) mz[tid + i * 256] = z;
  }
  const int lane = tid & 63, wv = tid >> 6;
  const int lr = lane & 15, lg = lane >> 4;
  const int arow = n0 + wv * 16 + lr;
  bf16x8 a[4];
#pragma unroll
  for (int ks = 0; ks < 4; ++ks)
    a[ks] = *(const bf16x8*)(hbf + (size_t)arow * HD + ks * 32 + lg * 8);
  const f32x4 zero = {0.f, 0.f, 0.f, 0.f};
  f32x4 acc[16];
#pragma unroll
  for (int i = 0; i < 16; ++i) acc[i] = zero;
#pragma unroll
  for (int ks = 0; ks < 4; ++ks){
#pragma unroll
    for (int ct = 0; ct < 16; ++ct){
      const int oct = ks * 4 + lg + ((ct >= 8) ? 16 : 0);
      const int ncol = (ct & 7) * 16 + lr;
      bf16x8 b = *(const bf16x8*)(W1p + ((size_t)oct * HD + ncol) * 8);
      acc[ct] = __builtin_amdgcn_mfma_f32_16x16x32_bf16(a[ks], b, acc[ct], 0, 0, 0);
    }
  }
#pragma unroll
  for (int ct = 0; ct < 16; ++ct){
    __half* dstp = (ct < 8) ? prea : preb;
    const int ncol = (ct & 7) * 16 + lr;
#pragma unroll
    for (int r = 0; r < 4; ++r){
      const int nrow = n0 + wv * 16 + lg * 4 + r;
      dstp[(size_t)nrow * HD + ncol] = __float2half_rn(acc[ct][r]);
    }
  }
}

// ---------------- per-layer bond-combo contribution: ecb = ebf@W1c + b1 (f16) ----------------
__global__ __launch_bounds__(256) void ew1c_k(
    const ushort* __restrict__ ebf, const ushort* __restrict__ W1p_all,
    const float* __restrict__ b1_all, __half* __restrict__ ecb_all)
{
  const int l = blockIdx.y;
  const ushort* W1p = W1p_all + (size_t)l * 384 * HD;
  const float* b1v = b1_all + l * HD;
  __half* ecb = ecb_all + (size_t)l * 512 * HD;
  const int tid = threadIdx.x;
  const int c0 = blockIdx.x * 64;
  const int lane = tid & 63, wv = tid >> 6;
  const int lr = lane & 15, lg = lane >> 4;
  const int arow = c0 + wv * 16 + lr;
  bf16x8 a[4];
#pragma unroll
  for (int ks = 0; ks < 4; ++ks)
    a[ks] = *(const bf16x8*)(ebf + (size_t)arow * HD + ks * 32 + lg * 8);
  const f32x4 zero = {0.f, 0.f, 0.f, 0.f};
  f32x4 acc[8];
#pragma unroll
  for (int i = 0; i < 8; ++i) acc[i] = zero;
#pragma unroll
  for (int ks = 0; ks < 4; ++ks){
#pragma unroll
    for (int ct = 0; ct < 8; ++ct){
      const int oct = ks * 4 + lg + 32;
      const int ncol = ct * 16 + lr;
      bf16x8 b = *(const bf16x8*)(W1p + ((size_t)oct * HD + ncol) * 8);
      acc[ct] = __builtin_amdgcn_mfma_f32_16x16x32_bf16(a[ks], b, acc[ct], 0, 0, 0);
    }
  }
#pragma unroll
  for (int ct = 0; ct < 8; ++ct){
    const int ncol = ct * 16 + lr;
    const float bias = b1v[ncol];
#pragma unroll
    for (int r = 0; r < 4; ++r){
      const int nrow = c0 + wv * 16 + lg * 4 + r;
      ecb[(size_t)nrow * HD + ncol] = __float2half_rn(acc[ct][r] + bias);
    }
  }
}

// ---------------- fused edge kernel: 128 edges/block, 2 tiles/wave sharing B ----------------
__device__ __forceinline__ void build_af(
    const __half* __restrict__ prea, const __half* __restrict__ preb,
    const __half* __restrict__ ecb, int s, int d, int c, int lg, f16x8* af)
{
#pragma unroll
  for (int ks = 0; ks < 4; ++ks){
    const int off = ks * 32 + lg * 8;
    union { uint4 q; __half2 h[4]; f16x8 v; } ua, ub, uc, uo;
    ua.q = *(const uint4*)(prea + (size_t)s * HD + off);
    ub.q = *(const uint4*)(preb + (size_t)d * HD + off);
    uc.q = *(const uint4*)(ecb + (size_t)c * HD + off);
#pragma unroll
    for (int j = 0; j < 4; ++j)
      uo.h[j] = silu_h2(__hadd2(__hadd2(ua.h[j], ub.h[j]), uc.h[j]));
    af[ks] = uo.v;
  }
}

// epilogue (silu+gate) then in-register segmented accumulate over this thread's
// 4 sorted rows; one packed-f16 atomic per (run, col-pair)
__device__ __forceinline__ void edge_finish(
    const f32x4* acc, int lr, int lg, int e0, int rowbase,
    const int* __restrict__ dst_p,
    const float* b2l, const float* b2h, const __half2* gwh, float gbias,
    __half2* __restrict__ msum2)
{
  __half2 mh[4][4];
#pragma unroll
  for (int ct = 0; ct < 4; ++ct){
#pragma unroll
    for (int r = 0; r < 4; ++r)
      mh[ct][r] = silu_h2(pkrtz(acc[ct][r] + b2l[ct], acc[ct + 4][r] + b2h[ct]));
  }
#pragma unroll
  for (int r = 0; r < 4; ++r){
    float sgs = 0.f;
#pragma unroll
    for (int ct = 0; ct < 4; ++ct){
      H2U a, b; a.h = mh[ct][r]; b.h = gwh[ct];
      sgs = __builtin_amdgcn_fdot2(a.v, b.v, sgs, false);
    }
    sgs += __shfl_xor(sgs, 1); sgs += __shfl_xor(sgs, 2);
    sgs += __shfl_xor(sgs, 4); sgs += __shfl_xor(sgs, 8);
    const __half2 gh = __float2half2_rn(sigmf(sgs + gbias));
#pragma unroll
    for (int ct = 0; ct < 4; ++ct) mh[ct][r] = __hmul2(mh[ct][r], gh);
  }
  // dst for this thread's 4 rows (broadcast across the 16 lanes sharing lg)
  const int rb = e0 + rowbase + lg * 4;
  int dl[4];
#pragma unroll
  for (int r = 0; r < 4; ++r) dl[r] = dst_p[rb + r];
#pragma unroll
  for (int ct = 0; ct < 4; ++ct){
    const int cp = ct * 16 + lr;
    float rl = __low2float(mh[ct][0]), rh = __high2float(mh[ct][0]);
    int cur = dl[0];
#pragma unroll
    for (int r = 1; r < 4; ++r){
      if (dl[r] == cur){
        rl += __low2float(mh[ct][r]); rh += __high2float(mh[ct][r]);
      } else {
        unsafeAtomicAdd(&msum2[(size_t)cur * 64 + cp], pkrtz(rl, rh));
        rl = __low2float(mh[ct][r]); rh = __high2float(mh[ct][r]);
        cur = dl[r];
      }
    }
    unsafeAtomicAdd(&msum2[(size_t)cur * 64 + cp], pkrtz(rl, rh));
  }
}

__global__ __launch_bounds__(256, 4) void msg2_kernel(
    const __half* __restrict__ prea, const __half* __restrict__ preb,
    const __half* __restrict__ ecb,
    const int* __restrict__ esrc_p, const int* __restrict__ dst_p,
    const int* __restrict__ cid_p,
    const __half* __restrict__ W2p, const float* __restrict__ b2v,
    const float* __restrict__ gw, const float* __restrict__ gb,
    __half2* __restrict__ msum2)
{
  const int tid = threadIdx.x;
  // chunked XCD swizzle (bijective: NBLK2 % 8 == 0)
  const int bid = (int)blockIdx.x;
  const int bsw = (bid & 7) * (NBLK2 >> 3) + (bid >> 3);
  const int e0 = bsw * 128;

  const int lane = tid & 63;
  const int wv = tid >> 6;
  const int lr = lane & 15, lg = lane >> 4;
  const int row0 = e0 + wv * 16 + lr;       // tile 0 edge row
  const int row1 = row0 + 64;               // tile 1 edge row
  const int s0 = esrc_p[row0], d0 = dst_p[row0], c0 = cid_p[row0];
  const int s1 = esrc_p[row1], d1 = dst_p[row1], c1 = cid_p[row1];

  f16x8 af0[4], af1[4];
  build_af(prea, preb, ecb, s0, d0, c0, lg, af0);
  build_af(prea, preb, ecb, s1, d1, c1, lg, af1);

  // GEMM2 for both tiles, one B-load per (ks,ct)
  const f32x4 zero = {0.f, 0.f, 0.f, 0.f};
  f32x4 acc0[8], acc1[8];
#pragma unroll
  for (int i = 0; i < 8; ++i){ acc0[i] = zero; acc1[i] = zero; }
#pragma unroll
  for (int ks = 0; ks < 4; ++ks){
    const __half* wb = W2p + ((size_t)(ks * 4 + lg) * HD + lr) * 8;
#pragma unroll
    for (int ct = 0; ct < 8; ++ct){
      f16x8 b = *(const f16x8*)(wb + ct * 16 * 8);
      acc0[ct] = __builtin_amdgcn_mfma_f32_16x16x32_f16(af0[ks], b, acc0[ct], 0, 0, 0);
      acc1[ct] = __builtin_amdgcn_mfma_f32_16x16x32_f16(af1[ks], b, acc1[ct], 0, 0, 0);
    }
  }

  float b2l[4], b2h[4];
  __half2 gwh[4];
#pragma unroll
  for (int ct = 0; ct < 4; ++ct){
    b2l[ct] = b2v[ct * 16 + lr];
    b2h[ct] = b2v[ct * 16 + lr + 64];
    gwh[ct] = pkrtz(gw[ct * 16 + lr], gw[ct * 16 + lr + 64]);
  }
  const float gbias = gb[0];
  edge_finish(acc0, lr, lg, e0, wv * 16, dst_p, b2l, b2h, gwh, gbias, msum2);
  edge_finish(acc1, lr, lg, e0, 64 + wv * 16, dst_p, b2l, b2h, gwh, gbias, msum2);
}

// ---------------- fused node MLP (64 nodes/block) ----------------
// MODE 0: A = bf16(h + msum); out = silu(A@W1+b1)@W2 + b2 + h -> h, hbf
// MODE 1: A = bf16(h);        out = silu(A@W1+b1)@W2 + b2     -> outp
template <int MODE>
__global__ __launch_bounds__(256) void node_mlp(
    const float* hin, const uint* __restrict__ msum2,
    const ushort* __restrict__ W1p, const ushort* __restrict__ W2p,
    const float* __restrict__ b1v, const float* __restrict__ b2v,
    float* outp, ushort* __restrict__ hbf)
{
  __shared__ ushort At[64 * 128];
  __shared__ ushort Tt[64 * 128];
  const int tid = threadIdx.x;
  const int n0 = blockIdx.x * 64;

  { // stage: 4 threads per node, 32 cols each
    const int nl = tid >> 2, part = tid & 3;
    const int node = n0 + nl;
    const float4* hp = (const float4*)(hin + (size_t)node * HD + part * 32);
    // msum2 pairs: pair cp holds cols (cp, cp+64); part 0,1 -> lo halves, part 2,3 -> hi
    const uint* mp = (MODE == 0) ? (msum2 + (size_t)node * 64) : nullptr;
    const bool hiHalf = (MODE == 0) && (part >= 2);
    char* rowp = (char*)At + nl * 256;
    const uint sw = (uint)((nl & 7) << 4);
#pragma unroll
    for (int j = 0; j < 4; ++j){
      float4 x0 = hp[j * 2 + 0], x1 = hp[j * 2 + 1];
      if (MODE == 0){
        const int cp0 = (part & 1) * 32 + j * 8;
        uint4 ma = *(const uint4*)(mp + cp0);
        uint4 mb = *(const uint4*)(mp + cp0 + 4);
        H2U w0, w1, w2, w3, w4, w5, w6, w7;
        w0.u = ma.x; w1.u = ma.y; w2.u = ma.z; w3.u = ma.w;
        w4.u = mb.x; w5.u = mb.y; w6.u = mb.z; w7.u = mb.w;
        if (hiHalf){
          x0.x += __high2float(w0.h); x0.y += __high2float(w1.h);
          x0.z += __high2float(w2.h); x0.w += __high2float(w3.h);
          x1.x += __high2float(w4.h); x1.y += __high2float(w5.h);
          x1.z += __high2float(w6.h); x1.w += __high2float(w7.h);
        } else {
          x0.x += __low2float(w0.h); x0.y += __low2float(w1.h);
          x0.z += __low2float(w2.h); x0.w += __low2float(w3.h);
          x1.x += __low2float(w4.h); x1.y += __low2float(w5.h);
          x1.z += __low2float(w6.h); x1.w += __low2float(w7.h);
        }
      }
      uint4 o;
      o.x = packbf2(x0.x, x0.y); o.y = packbf2(x0.z, x0.w);
      o.z = packbf2(x1.x, x1.y); o.w = packbf2(x1.z, x1.w);
      uint cb = (uint)(part * 64 + j * 16);
      *(uint4*)(rowp + (cb ^ sw)) = o;
    }
  }
  __syncthreads();

  const int lane = tid & 63;
  const int wv = tid >> 6;
  const int lr = lane & 15, lg = lane >> 4;
  const int rowbase = wv * 16;
  const f32x4 zero = {0.f, 0.f, 0.f, 0.f};
  const int arow = rowbase + lr;
  const char* arp = (const char*)At + arow * 256;
  const uint asw = (uint)((arow & 7) << 4);

  f32x4 acc[8];
#pragma unroll
  for (int i = 0; i < 8; ++i) acc[i] = zero;
#pragma unroll
  for (int ks = 0; ks < 4; ++ks){
    uint cb = (uint)(ks * 64 + lg * 16);
    bf16x8 a = *(const bf16x8*)(arp + (cb ^ asw));
    const ushort* wbase = W1p + ((size_t)(ks * 4 + lg) * 128 + lr) * 8;
#pragma unroll
    for (int ct = 0; ct < 8; ++ct){
      bf16x8 b = *(const bf16x8*)(wbase + ct * 16 * 8);
      acc[ct] = __builtin_amdgcn_mfma_f32_16x16x32_bf16(a, b, acc[ct], 0, 0, 0);
    }
  }
#pragma unroll
  for (int ct = 0; ct < 8; ++ct){
    const int col = ct * 16 + lr;
    const float bias = b1v[col];
#pragma unroll
    for (int r = 0; r < 4; ++r){
      const int row = rowbase + lg * 4 + r;
      float v = siluf(acc[ct][r] + bias);
      *(ushort*)((char*)Tt + row * 256 + (((uint)(col * 2)) ^ ((uint)(row & 7) << 4))) = f2bf(v);
    }
  }
  __syncthreads();

  f32x4 acc2[8];
#pragma unroll
  for (int i = 0; i < 8; ++i) acc2[i] = zero;
  {
    const char* trp = (const char*)Tt + arow * 256;
#pragma unroll
    for (int ks = 0; ks < 4; ++ks){
      uint cb = (uint)(ks * 64 + lg * 16);
      bf16x8 a = *(const bf16x8*)(trp + (cb ^ asw));
      const ushort* wbase = W2p + ((size_t)(ks * 4 + lg) * 128 + lr) * 8;
#pragma unroll
      for (int ct = 0; ct < 8; ++ct){
        bf16x8 b = *(const bf16x8*)(wbase + ct * 16 * 8);
        acc2[ct] = __builtin_amdgcn_mfma_f32_16x16x32_bf16(a, b, acc2[ct], 0, 0, 0);
      }
    }
  }
#pragma unroll
  for (int ct = 0; ct < 8; ++ct){
    const int col = ct * 16 + lr;
    const float bias = b2v[col];
#pragma unroll
    for (int r = 0; r < 4; ++r){
      const int node = n0 + rowbase + lg * 4 + r;
      float v = acc2[ct][r] + bias;
      if (MODE == 0) v += hin[(size_t)node * HD + col];
      outp[(size_t)node * HD + col] = v;
      if (MODE == 0) hbf[(size_t)node * HD + col] = f2bf(v);
    }
  }
}

// ---------------- fused per-graph readout + final MLP ----------------
__global__ __launch_bounds__(128) void readout_final(
    const float* __restrict__ hout, const int* __restrict__ n2g,
    const float* __restrict__ W1, const float* __restrict__ b1,
    const float* __restrict__ W2, const float* __restrict__ b2,
    float* __restrict__ out){
  __shared__ float rsh[384];
  __shared__ float hr[128];
  const int g = blockIdx.x;
  const int c = threadIdx.x; // 128
  int lo, hi;
  { int a = 0, b = NN; while (a < b){ int mid = (a + b) >> 1; if (n2g[mid] < g) a = mid + 1; else b = mid; } lo = a; }
  { int a = lo, b = NN; while (a < b){ int mid = (a + b) >> 1; if (n2g[mid] < g + 1) a = mid + 1; else b = mid; } hi = a; }
  float s = 0.f, mx = -3.4e38f;
  for (int n = lo; n < hi; ++n){
    float v = hout[(size_t)n * HD + c];
    s += v; mx = fmaxf(mx, v);
  }
  const int cnt = hi - lo;
  float mean = (cnt > 0) ? s / (float)cnt : 0.f;
  if (cnt == 0){ s = 0.f; mx = 0.f; }
  rsh[c] = s; rsh[128 + c] = mean; rsh[256 + c] = mx;
  __syncthreads();
  float acc = b1[c];
#pragma unroll 4
  for (int j = 0; j < 384; ++j) acc += rsh[j] * W1[j * 128 + c];
  hr[c] = fmaxf(acc, 0.f);
  __syncthreads();
  if (c < TD){
    float o = b2[c];
#pragma unroll 4
    for (int j = 0; j < 128; ++j) o += hr[j] * W2[j * TD + c];
    out[(size_t)g * TD + c] = o;
  }
}

extern "C" void kernel_launch(void* const* d_in, const int* in_sizes, int n_in,
                              void* d_out, int out_size, void* d_ws, size_t ws_size,
                              hipStream_t stream)
{
  const int*   atom_feat  = (const int*)  d_in[0];
  const int*   bond_feat  = (const int*)  d_in[1];
  const int*   edge_src   = (const int*)  d_in[2];
  const int*   edge_dst   = (const int*)  d_in[3];
  const int*   node2graph = (const int*)  d_in[4];
  const float* atom_emb   = (const float*)d_in[5];
  const float* bond_emb   = (const float*)d_in[6];
  const float* msg_W1     = (const float*)d_in[7];
  const float* msg_b1     = (const float*)d_in[8];
  const float* msg_W2     = (const float*)d_in[9];
  const float* msg_b2     = (const float*)d_in[10];
  const float* gate_W     = (const float*)d_in[11];
  const float* gate_b     = (const float*)d_in[12];
  const float* upd_W1     = (const float*)d_in[13];
  const float* upd_b1     = (const float*)d_in[14];
  const float* upd_W2     = (const float*)d_in[15];
  const float* upd_b2     = (const float*)d_in[16];
  const float* out_W1     = (const float*)d_in[17];
  const float* out_b1     = (const float*)d_in[18];
  const float* out_W2     = (const float*)d_in[19];
  const float* out_b2     = (const float*)d_in[20];
  const float* ro_W1      = (const float*)d_in[21];
  const float* ro_b1      = (const float*)d_in[22];
  const float* ro_W2      = (const float*)d_in[23];
  const float* ro_b2      = (const float*)d_in[24];
  (void)in_sizes; (void)n_in; (void)out_size; (void)ws_size;

  char* ws = (char*)d_ws;
  size_t off = 0;
  auto alloc = [&](size_t bytes) -> char* {
    char* p = ws + off;
    off = (off + bytes + 255) & ~(size_t)255;
    return p;
  };
  float*   h      = (float*)  alloc((size_t)NN * HD * 4);
  float*   hout   = (float*)  alloc((size_t)NN * HD * 4);
  ushort*  hbf    = (ushort*) alloc((size_t)NN * HD * 2);
  __half2* msum2  = (__half2*)alloc((size_t)NN * 64 * 4);
  ushort*  msgW1p = (ushort*) alloc((size_t)DEPTH * 384 * HD * 2);
  ushort*  msgW2p = (ushort*) alloc((size_t)DEPTH * HD * HD * 2); // f16
  ushort*  updW1p = (ushort*) alloc((size_t)DEPTH * HD * HD * 2);
  ushort*  updW2p = (ushort*) alloc((size_t)DEPTH * HD * HD * 2);
  ushort*  outW1p = (ushort*) alloc((size_t)HD * HD * 2);
  ushort*  outW2p = (ushort*) alloc((size_t)HD * HD * 2);
  ushort*  ebf    = (ushort*) alloc((size_t)512 * HD * 2);
  __half*  ecb    = (__half*) alloc((size_t)DEPTH * 512 * HD * 2);
  __half*  prea   = (__half*) alloc((size_t)NN * HD * 2);
  __half*  preb   = (__half*) alloc((size_t)NN * HD * 2);
  int*     deg    = (int*)    alloc((size_t)NN * 4);
  int*     head   = (int*)    alloc((size_t)NN * 4);
  int*     esrc_p = (int*)    alloc((size_t)NE * 4);
  int*     dst_p  = (int*)    alloc((size_t)NE * 4);
  int*     cid_p  = (int*)    alloc((size_t)NE * 4);

  pack6<<<dim3(48, 6), 256, 0, stream>>>(msg_W1, msg_W2, upd_W1, upd_W2, out_W1, out_W2,
                                         msgW1p, msgW2p, updW1p, updW2p, outW1p, outW2p);
  atom_encode<<<NN, HD, 0, stream>>>(atom_feat, atom_emb, h, hbf);
  ebf_k<<<512, HD, 0, stream>>>(bond_emb, ebf);
  ew1c_k<<<dim3(8, DEPTH), 256, 0, stream>>>(ebf, msgW1p, msg_b1, ecb);

  // counting sort of edges by dst
  zero_i<<<160, 256, 0, stream>>>(deg, NN);
  hist_k<<<640, 256, 0, stream>>>(edge_dst, deg);
  scan_head<<<1, 1024, 0, stream>>>(deg, head);
  scatter_k<<<640, 256, 0, stream>>>(edge_src, edge_dst, bond_feat, head,
                                     esrc_p, dst_p, cid_p);

  for (int l = 0; l < DEPTH; ++l){
    pre_k<<<NN / 64, 256, 0, stream>>>(hbf, msgW1p + (size_t)l * 384 * HD, prea, preb,
                                       (uint*)msum2);
    msg2_kernel<<<NBLK2, 256, 0, stream>>>(
        prea, preb, ecb + (size_t)l * 512 * HD,
        esrc_p, dst_p, cid_p,
        (const __half*)msgW2p + (size_t)l * HD * HD,
        msg_b2 + l * HD, gate_W + l * HD, gate_b + l, msum2);
    node_mlp<0><<<NN / 64, 256, 0, stream>>>(
        h, (const uint*)msum2,
        updW1p + (size_t)l * HD * HD, updW2p + (size_t)l * HD * HD,
        upd_b1 + l * HD, upd_b2 + l * HD, h, hbf);
  }
  node_mlp<1><<<NN / 64, 256, 0, stream>>>(
      h, nullptr, outW1p, outW2p, out_b1, out_b2, hout, nullptr);
  readout_final<<<NG, 128, 0, stream>>>(hout, node2graph, ro_W1, ro_b1, ro_W2, ro_b2,
                                        (float*)d_out);
}

// Round 14
// 708.336 us; speedup vs baseline: 1.2816x; 1.2816x over previous
//
#include <hip/hip_runtime.h>
#include <hip/hip_bf16.h>
#include <hip/hip_fp16.h>

#define NN 40000
#define NE 640000
#define HD 128
#define DEPTH 4
#define NG 1250
#define TD 32
#define AFN 9
#define AVN 64
#define BFN 3
#define BVN 8
#define NBLK2 (NE / 128)   // 5000, divisible by 8

typedef short bf16x8 __attribute__((ext_vector_type(8)));
typedef _Float16 f16x8 __attribute__((ext_vector_type(8)));
typedef _Float16 f16x2 __attribute__((ext_vector_type(2)));
typedef float f32x4 __attribute__((ext_vector_type(4)));

__device__ __forceinline__ uint cvtpk(float lo, float hi){
  uint r; asm("v_cvt_pk_bf16_f32 %0, %1, %2" : "=v"(r) : "v"(lo), "v"(hi)); return r;
}
__device__ __forceinline__ ushort f2bf(float x){ return (ushort)cvtpk(x, x); }
__device__ __forceinline__ float rcpfa(float x){ return __builtin_amdgcn_rcpf(x); }
__device__ __forceinline__ float siluf(float x){ return x * rcpfa(1.f + __expf(-x)); }
__device__ __forceinline__ float sigmf(float x){ return rcpfa(1.f + __expf(-x)); }
__device__ __forceinline__ uint packbf2(float a, float b){ return cvtpk(a, b); }

__device__ __forceinline__ __half2 silu_h2(__half2 x){
  const __half2 nl2e = __float2half2_rn(-1.44269504f);
  const __half2 one  = __float2half2_rn(1.f);
  __half2 e = h2exp2(__hmul2(x, nl2e));
  return __hmul2(x, h2rcp(__hadd2(one, e)));
}
union H2U { __half2 h; f16x2 v; uint u; };
__device__ __forceinline__ __half2 pkrtz(float lo, float hi){
  auto t = __builtin_amdgcn_cvt_pkrtz(lo, hi);
  H2U r; __builtin_memcpy(&r.u, &t, 4); return r.h;
}

// ---------------- pack all weights in one launch ----------------
__device__ __forceinline__ void pack_one(const float* __restrict__ src,
                                         ushort* __restrict__ dst,
                                         int K, int L, int isf16){
  int total = L * K * HD;
  for (int idx = blockIdx.x * blockDim.x + threadIdx.x; idx < total;
       idx += gridDim.x * blockDim.x){
    int l = idx / (K * HD);
    int r = idx - l * K * HD;
    int k = r / HD;
    int n = r - k * HD;
    float v = src[idx];
    ushort o;
    if (isf16){ __half hv = __float2half_rn(v); o = *(ushort*)&hv; }
    else o = f2bf(v);
    dst[(size_t)l * K * HD + ((size_t)(k >> 3) * HD + n) * 8 + (k & 7)] = o;
  }
}
__global__ void pack6(const float* s0, const float* s1, const float* s2,
                      const float* s3, const float* s4, const float* s5,
                      ushort* d0, ushort* d1, ushort* d2,
                      ushort* d3, ushort* d4, ushort* d5){
  switch (blockIdx.y){
    case 0: pack_one(s0, d0, 384, DEPTH, 0); break;
    case 1: pack_one(s1, d1, HD, DEPTH, 1); break;
    case 2: pack_one(s2, d2, HD, DEPTH, 0); break;
    case 3: pack_one(s3, d3, HD, DEPTH, 0); break;
    case 4: pack_one(s4, d4, HD, 1, 0); break;
    default: pack_one(s5, d5, HD, 1, 0); break;
  }
}

__global__ void zero_i(int* __restrict__ p, int n){
  for (int i = blockIdx.x * blockDim.x + threadIdx.x; i < n; i += gridDim.x * blockDim.x)
    p[i] = 0;
}

// ---------------- atom encoder ----------------
__global__ void atom_encode(const int* __restrict__ feat, const float* __restrict__ emb,
                            float* __restrict__ h, ushort* __restrict__ hbf){
  int n = blockIdx.x;
  int c = threadIdx.x; // 128
  float acc = 0.f;
#pragma unroll
  for (int f = 0; f < AFN; ++f){
    int v = feat[n * AFN + f];
    acc += emb[(size_t)(f * AVN + v) * HD + c];
  }
  h[(size_t)n * HD + c] = acc;
  hbf[(size_t)n * HD + c] = f2bf(acc);
}

// ---------------- bond combo table: ebf[512][128] bf16 ----------------
__global__ void ebf_k(const float* __restrict__ bemb, ushort* __restrict__ ebf){
  const int cid = blockIdx.x;      // 512
  const int c = threadIdx.x;       // 128
  const int f0 = cid >> 6, f1 = (cid >> 3) & 7, f2 = cid & 7;
  float v = bemb[(size_t)(0 * BVN + f0) * HD + c]
          + bemb[(size_t)(1 * BVN + f1) * HD + c]
          + bemb[(size_t)(2 * BVN + f2) * HD + c];
  ebf[(size_t)cid * HD + c] = f2bf(v);
}

// ---------------- edge histogram by dst ----------------
__global__ void hist_k(const int* __restrict__ edst, int* __restrict__ deg){
  for (int e = blockIdx.x * blockDim.x + threadIdx.x; e < NE; e += gridDim.x * blockDim.x)
    atomicAdd(&deg[edst[e]], 1);
}

// ---------------- exclusive scan over NN=40000 (single block, 1024 thr) ----------------
__global__ __launch_bounds__(1024) void scan_head(const int* __restrict__ deg,
                                                  int* __restrict__ head){
  __shared__ int buf[1024];
  const int t = threadIdx.x;
  const int base = t * 40;
  int s = 0;
  int dloc[40];
  if (t < 1000){
#pragma unroll
    for (int i = 0; i < 40; ++i){ dloc[i] = deg[base + i]; s += dloc[i]; }
  }
  buf[t] = s;
  __syncthreads();
  for (int ofs = 1; ofs < 1024; ofs <<= 1){
    int x = (t >= ofs) ? buf[t - ofs] : 0;
    __syncthreads();
    buf[t] += x;
    __syncthreads();
  }
  if (t < 1000){
    int run = buf[t] - s;
#pragma unroll
    for (int i = 0; i < 40; ++i){ head[base + i] = run; run += dloc[i]; }
  }
}

// ---------------- scatter edges into dst-sorted order ----------------
// pc = (cid<<16) | dst   (dst < 65536, cid < 512)
__global__ void scatter_k(const int* __restrict__ esrc, const int* __restrict__ edst,
                          const int* __restrict__ bfeat, int* __restrict__ head,
                          int* __restrict__ esrc_p, int* __restrict__ pc_p){
  for (int e = blockIdx.x * blockDim.x + threadIdx.x; e < NE; e += gridDim.x * blockDim.x){
    const int d = edst[e];
    const int pos = atomicAdd(&head[d], 1);
    const int cid = bfeat[e * 3 + 0] * 64 + bfeat[e * 3 + 1] * 8 + bfeat[e * 3 + 2];
    esrc_p[pos] = esrc[e];
    pc_p[pos] = (cid << 16) | d;
  }
}

// ---------------- per-layer node precompute: prea/preb = hbf@W1a/b (f16) + zero msum ----------------
__global__ __launch_bounds__(256) void pre_k(
    const ushort* __restrict__ hbf, const ushort* __restrict__ W1p,
    __half* __restrict__ prea, __half* __restrict__ preb,
    uint* __restrict__ msum2)
{
  const int tid = threadIdx.x;
  const int n0 = blockIdx.x * 64;
  { // zero this block's msum2 rows (64 nodes x 64 pairs = 1024 uint4)
    uint4* mz = (uint4*)(msum2 + (size_t)n0 * 64);
    const uint4 z = make_uint4(0u, 0u, 0u, 0u);
#pragma unroll
    for (int i = 0; i < 4; ++i) mz[tid + i * 256] = z;
  }
  const int lane = tid & 63, wv = tid >> 6;
  const int lr = lane & 15, lg = lane >> 4;
  const int arow = n0 + wv * 16 + lr;
  bf16x8 a[4];
#pragma unroll
  for (int ks = 0; ks < 4; ++ks)
    a[ks] = *(const bf16x8*)(hbf + (size_t)arow * HD + ks * 32 + lg * 8);
  const f32x4 zero = {0.f, 0.f, 0.f, 0.f};
  f32x4 acc[16];
#pragma unroll
  for (int i = 0; i < 16; ++i) acc[i] = zero;
#pragma unroll
  for (int ks = 0; ks < 4; ++ks){
#pragma unroll
    for (int ct = 0; ct < 16; ++ct){
      const int oct = ks * 4 + lg + ((ct >= 8) ? 16 : 0);
      const int ncol = (ct & 7) * 16 + lr;
      bf16x8 b = *(const bf16x8*)(W1p + ((size_t)oct * HD + ncol) * 8);
      acc[ct] = __builtin_amdgcn_mfma_f32_16x16x32_bf16(a[ks], b, acc[ct], 0, 0, 0);
    }
  }
#pragma unroll
  for (int ct = 0; ct < 16; ++ct){
    __half* dstp = (ct < 8) ? prea : preb;
    const int ncol = (ct & 7) * 16 + lr;
#pragma unroll
    for (int r = 0; r < 4; ++r){
      const int nrow = n0 + wv * 16 + lg * 4 + r;
      dstp[(size_t)nrow * HD + ncol] = __float2half_rn(acc[ct][r]);
    }
  }
}

// ---------------- per-layer bond-combo contribution: ecb = ebf@W1c + b1 (f16) ----------------
__global__ __launch_bounds__(256) void ew1c_k(
    const ushort* __restrict__ ebf, const ushort* __restrict__ W1p_all,
    const float* __restrict__ b1_all, __half* __restrict__ ecb_all)
{
  const int l = blockIdx.y;
  const ushort* W1p = W1p_all + (size_t)l * 384 * HD;
  const float* b1v = b1_all + l * HD;
  __half* ecb = ecb_all + (size_t)l * 512 * HD;
  const int tid = threadIdx.x;
  const int c0 = blockIdx.x * 64;
  const int lane = tid & 63, wv = tid >> 6;
  const int lr = lane & 15, lg = lane >> 4;
  const int arow = c0 + wv * 16 + lr;
  bf16x8 a[4];
#pragma unroll
  for (int ks = 0; ks < 4; ++ks)
    a[ks] = *(const bf16x8*)(ebf + (size_t)arow * HD + ks * 32 + lg * 8);
  const f32x4 zero = {0.f, 0.f, 0.f, 0.f};
  f32x4 acc[8];
#pragma unroll
  for (int i = 0; i < 8; ++i) acc[i] = zero;
#pragma unroll
  for (int ks = 0; ks < 4; ++ks){
#pragma unroll
    for (int ct = 0; ct < 8; ++ct){
      const int oct = ks * 4 + lg + 32;
      const int ncol = ct * 16 + lr;
      bf16x8 b = *(const bf16x8*)(W1p + ((size_t)oct * HD + ncol) * 8);
      acc[ct] = __builtin_amdgcn_mfma_f32_16x16x32_bf16(a[ks], b, acc[ct], 0, 0, 0);
    }
  }
#pragma unroll
  for (int ct = 0; ct < 8; ++ct){
    const int ncol = ct * 16 + lr;
    const float bias = b1v[ncol];
#pragma unroll
    for (int r = 0; r < 4; ++r){
      const int nrow = c0 + wv * 16 + lg * 4 + r;
      ecb[(size_t)nrow * HD + ncol] = __float2half_rn(acc[ct][r] + bias);
    }
  }
}

// ---------------- fused edge kernel: 128 edges/block, 2 tiles/wave sharing B ----------------
__device__ __forceinline__ void build_af(
    const __half* __restrict__ prea, const __half* __restrict__ preb,
    const __half* __restrict__ ecb, int s, int d, int c, int lg, f16x8* af)
{
#pragma unroll
  for (int ks = 0; ks < 4; ++ks){
    const int off = ks * 32 + lg * 8;
    union { uint4 q; __half2 h[4]; f16x8 v; } ua, ub, uc, uo;
    ua.q = *(const uint4*)(prea + (size_t)s * HD + off);
    ub.q = *(const uint4*)(preb + (size_t)d * HD + off);
    uc.q = *(const uint4*)(ecb + (size_t)c * HD + off);
#pragma unroll
    for (int j = 0; j < 4; ++j)
      uo.h[j] = silu_h2(__hadd2(__hadd2(ua.h[j], ub.h[j]), uc.h[j]));
    af[ks] = uo.v;
  }
}

__device__ __forceinline__ void edge_epilogue(
    f32x4* acc, int lr, int lg, int rowbase,
    const float* b2l, const float* b2h, const __half2* gwh, float gbias,
    uint* Ms)
{
  __half2 mh[4][4];
#pragma unroll
  for (int ct = 0; ct < 4; ++ct){
#pragma unroll
    for (int r = 0; r < 4; ++r)
      mh[ct][r] = silu_h2(pkrtz(acc[ct][r] + b2l[ct], acc[ct + 4][r] + b2h[ct]));
  }
#pragma unroll
  for (int r = 0; r < 4; ++r){
    float sgs = 0.f;
#pragma unroll
    for (int ct = 0; ct < 4; ++ct){
      H2U a, b; a.h = mh[ct][r]; b.h = gwh[ct];
      sgs = __builtin_amdgcn_fdot2(a.v, b.v, sgs, false);
    }
    sgs += __shfl_xor(sgs, 1); sgs += __shfl_xor(sgs, 2);
    sgs += __shfl_xor(sgs, 4); sgs += __shfl_xor(sgs, 8);
    const __half2 gh = __float2half2_rn(sigmf(sgs + gbias));
#pragma unroll
    for (int ct = 0; ct < 4; ++ct) mh[ct][r] = __hmul2(mh[ct][r], gh);
  }
#pragma unroll
  for (int ct = 0; ct < 4; ++ct){
    const int ui = ct * 16 + lr;
#pragma unroll
    for (int r = 0; r < 4; ++r){
      const int lrow = rowbase + lg * 4 + r;
      H2U w; w.h = mh[ct][r];
      *(uint*)((char*)Ms + lrow * 256 + (((uint)(ui * 4)) ^ ((uint)((lrow & 7) << 4)))) = w.u;
    }
  }
}

__global__ __launch_bounds__(256, 4) void msg2_kernel(
    const __half* __restrict__ prea, const __half* __restrict__ preb,
    const __half* __restrict__ ecb,
    const int* __restrict__ esrc_p, const int* __restrict__ pc_p,
    const __half* __restrict__ W2p, const float* __restrict__ b2v,
    const float* __restrict__ gw, const float* __restrict__ gb,
    __half2* __restrict__ msum2)
{
  __shared__ uint Ms[128 * 64]; // parked m pairs for 128 edges; row stride 256B, swizzled
  __shared__ int dsh[128];
  const int tid = threadIdx.x;
  // chunked XCD swizzle (bijective: NBLK2 % 8 == 0)
  const int bid = (int)blockIdx.x;
  const int bsw = (bid & 7) * (NBLK2 >> 3) + (bid >> 3);
  const int e0 = bsw * 128;
  if (tid < 128) dsh[tid] = pc_p[e0 + tid] & 0xffff;

  const int lane = tid & 63;
  const int wv = tid >> 6;
  const int lr = lane & 15, lg = lane >> 4;
  const int row0 = e0 + wv * 16 + lr;       // tile 0 edge row
  const int row1 = row0 + 64;               // tile 1 edge row
  const int s0 = esrc_p[row0], pc0 = pc_p[row0];
  const int s1 = esrc_p[row1], pc1 = pc_p[row1];

  f16x8 af0[4], af1[4];
  build_af(prea, preb, ecb, s0, pc0 & 0xffff, pc0 >> 16, lg, af0);
  build_af(prea, preb, ecb, s1, pc1 & 0xffff, pc1 >> 16, lg, af1);

  // GEMM2 for both tiles, one B-load per (ks,ct)
  const f32x4 zero = {0.f, 0.f, 0.f, 0.f};
  f32x4 acc0[8], acc1[8];
#pragma unroll
  for (int i = 0; i < 8; ++i){ acc0[i] = zero; acc1[i] = zero; }
#pragma unroll
  for (int ks = 0; ks < 4; ++ks){
    const __half* wb = W2p + ((size_t)(ks * 4 + lg) * HD + lr) * 8;
#pragma unroll
    for (int ct = 0; ct < 8; ++ct){
      f16x8 b = *(const f16x8*)(wb + ct * 16 * 8);
      acc0[ct] = __builtin_amdgcn_mfma_f32_16x16x32_f16(af0[ks], b, acc0[ct], 0, 0, 0);
      acc1[ct] = __builtin_amdgcn_mfma_f32_16x16x32_f16(af1[ks], b, acc1[ct], 0, 0, 0);
    }
  }

  float b2l[4], b2h[4];
  __half2 gwh[4];
#pragma unroll
  for (int ct = 0; ct < 4; ++ct){
    b2l[ct] = b2v[ct * 16 + lr];
    b2h[ct] = b2v[ct * 16 + lr + 64];
    gwh[ct] = pkrtz(gw[ct * 16 + lr], gw[ct * 16 + lr + 64]);
  }
  const float gbias = gb[0];
  edge_epilogue(acc0, lr, lg, wv * 16, b2l, b2h, gwh, gbias, Ms);
  edge_epilogue(acc1, lr, lg, 64 + wv * 16, b2l, b2h, gwh, gbias, Ms);
  __syncthreads();

  // segmented reduction: 64 col-pairs x 4 row-segments of 32; one packed-f16 atomic per run
  {
    const int cp = tid & 63;
    const int seg = tid >> 6;
    const int r0 = seg * 32, r1 = r0 + 32;
    float rl = 0.f, rh = 0.f;
    int cur = dsh[r0];
    for (int r = r0; r < r1; ++r){
      const int dd = dsh[r];
      if (dd != cur){
        unsafeAtomicAdd(&msum2[(size_t)cur * 64 + cp], pkrtz(rl, rh));
        rl = 0.f; rh = 0.f; cur = dd;
      }
      H2U w;
      w.u = *(const uint*)((const char*)Ms + r * 256 +
                           (((uint)(cp * 4)) ^ ((uint)((r & 7) << 4))));
      rl += __low2float(w.h); rh += __high2float(w.h);
    }
    unsafeAtomicAdd(&msum2[(size_t)cur * 64 + cp], pkrtz(rl, rh));
  }
}

// ---------------- fused node MLP (64 nodes/block) ----------------
// MODE 0: A = bf16(h + msum); out = silu(A@W1+b1)@W2 + b2 + h -> h, hbf
// MODE 1: A = bf16(h);        out = silu(A@W1+b1)@W2 + b2     -> outp
template <int MODE>
__global__ __launch_bounds__(256) void node_mlp(
    const float* hin, const uint* __restrict__ msum2,
    const ushort* __restrict__ W1p, const ushort* __restrict__ W2p,
    const float* __restrict__ b1v, const float* __restrict__ b2v,
    float* outp, ushort* __restrict__ hbf)
{
  __shared__ ushort At[64 * 128];
  __shared__ ushort Tt[64 * 128];
  const int tid = threadIdx.x;
  const int n0 = blockIdx.x * 64;

  { // stage: 4 threads per node, 32 cols each
    const int nl = tid >> 2, part = tid & 3;
    const int node = n0 + nl;
    const float4* hp = (const float4*)(hin + (size_t)node * HD + part * 32);
    const uint* mp = (MODE == 0) ? (msum2 + (size_t)node * 64) : nullptr;
    const bool hiHalf = (MODE == 0) && (part >= 2);
    char* rowp = (char*)At + nl * 256;
    const uint sw = (uint)((nl & 7) << 4);
#pragma unroll
    for (int j = 0; j < 4; ++j){
      float4 x0 = hp[j * 2 + 0], x1 = hp[j * 2 + 1];
      if (MODE == 0){
        const int cp0 = (part & 1) * 32 + j * 8;
        uint4 ma = *(const uint4*)(mp + cp0);
        uint4 mb = *(const uint4*)(mp + cp0 + 4);
        H2U w0, w1, w2, w3, w4, w5, w6, w7;
        w0.u = ma.x; w1.u = ma.y; w2.u = ma.z; w3.u = ma.w;
        w4.u = mb.x; w5.u = mb.y; w6.u = mb.z; w7.u = mb.w;
        if (hiHalf){
          x0.x += __high2float(w0.h); x0.y += __high2float(w1.h);
          x0.z += __high2float(w2.h); x0.w += __high2float(w3.h);
          x1.x += __high2float(w4.h); x1.y += __high2float(w5.h);
          x1.z += __high2float(w6.h); x1.w += __high2float(w7.h);
        } else {
          x0.x += __low2float(w0.h); x0.y += __low2float(w1.h);
          x0.z += __low2float(w2.h); x0.w += __low2float(w3.h);
          x1.x += __low2float(w4.h); x1.y += __low2float(w5.h);
          x1.z += __low2float(w6.h); x1.w += __low2float(w7.h);
        }
      }
      uint4 o;
      o.x = packbf2(x0.x, x0.y); o.y = packbf2(x0.z, x0.w);
      o.z = packbf2(x1.x, x1.y); o.w = packbf2(x1.z, x1.w);
      uint cb = (uint)(part * 64 + j * 16);
      *(uint4*)(rowp + (cb ^ sw)) = o;
    }
  }
  __syncthreads();

  const int lane = tid & 63;
  const int wv = tid >> 6;
  const int lr = lane & 15, lg = lane >> 4;
  const int rowbase = wv * 16;
  const f32x4 zero = {0.f, 0.f, 0.f, 0.f};
  const int arow = rowbase + lr;
  const char* arp = (const char*)At + arow * 256;
  const uint asw = (uint)((arow & 7) << 4);

  f32x4 acc[8];
#pragma unroll
  for (int i = 0; i < 8; ++i) acc[i] = zero;
#pragma unroll
  for (int ks = 0; ks < 4; ++ks){
    uint cb = (uint)(ks * 64 + lg * 16);
    bf16x8 a = *(const bf16x8*)(arp + (cb ^ asw));
    const ushort* wbase = W1p + ((size_t)(ks * 4 + lg) * 128 + lr) * 8;
#pragma unroll
    for (int ct = 0; ct < 8; ++ct){
      bf16x8 b = *(const bf16x8*)(wbase + ct * 16 * 8);
      acc[ct] = __builtin_amdgcn_mfma_f32_16x16x32_bf16(a, b, acc[ct], 0, 0, 0);
    }
  }
#pragma unroll
  for (int ct = 0; ct < 8; ++ct){
    const int col = ct * 16 + lr;
    const float bias = b1v[col];
#pragma unroll
    for (int r = 0; r < 4; ++r){
      const int row = rowbase + lg * 4 + r;
      float v = siluf(acc[ct][r] + bias);
      *(ushort*)((char*)Tt + row * 256 + (((uint)(col * 2)) ^ ((uint)(row & 7) << 4))) = f2bf(v);
    }
  }
  __syncthreads();

  f32x4 acc2[8];
#pragma unroll
  for (int i = 0; i < 8; ++i) acc2[i] = zero;
  {
    const char* trp = (const char*)Tt + arow * 256;
#pragma unroll
    for (int ks = 0; ks < 4; ++ks){
      uint cb = (uint)(ks * 64 + lg * 16);
      bf16x8 a = *(const bf16x8*)(trp + (cb ^ asw));
      const ushort* wbase = W2p + ((size_t)(ks * 4 + lg) * 128 + lr) * 8;
#pragma unroll
      for (int ct = 0; ct < 8; ++ct){
        bf16x8 b = *(const bf16x8*)(wbase + ct * 16 * 8);
        acc2[ct] = __builtin_amdgcn_mfma_f32_16x16x32_bf16(a, b, acc2[ct], 0, 0, 0);
      }
    }
  }
#pragma unroll
  for (int ct = 0; ct < 8; ++ct){
    const int col = ct * 16 + lr;
    const float bias = b2v[col];
#pragma unroll
    for (int r = 0; r < 4; ++r){
      const int node = n0 + rowbase + lg * 4 + r;
      float v = acc2[ct][r] + bias;
      if (MODE == 0) v += hin[(size_t)node * HD + col];
      outp[(size_t)node * HD + col] = v;
      if (MODE == 0) hbf[(size_t)node * HD + col] = f2bf(v);
    }
  }
}

// ---------------- fused per-graph readout + final MLP ----------------
__global__ __launch_bounds__(128) void readout_final(
    const float* __restrict__ hout, const int* __restrict__ n2g,
    const float* __restrict__ W1, const float* __restrict__ b1,
    const float* __restrict__ W2, const float* __restrict__ b2,
    float* __restrict__ out){
  __shared__ float rsh[384];
  __shared__ float hr[128];
  const int g = blockIdx.x;
  const int c = threadIdx.x; // 128
  int lo, hi;
  { int a = 0, b = NN; while (a < b){ int mid = (a + b) >> 1; if (n2g[mid] < g) a = mid + 1; else b = mid; } lo = a; }
  { int a = lo, b = NN; while (a < b){ int mid = (a + b) >> 1; if (n2g[mid] < g + 1) a = mid + 1; else b = mid; } hi = a; }
  float s = 0.f, mx = -3.4e38f;
  for (int n = lo; n < hi; ++n){
    float v = hout[(size_t)n * HD + c];
    s += v; mx = fmaxf(mx, v);
  }
  const int cnt = hi - lo;
  float mean = (cnt > 0) ? s / (float)cnt : 0.f;
  if (cnt == 0){ s = 0.f; mx = 0.f; }
  rsh[c] = s; rsh[128 + c] = mean; rsh[256 + c] = mx;
  __syncthreads();
  float acc = b1[c];
#pragma unroll 4
  for (int j = 0; j < 384; ++j) acc += rsh[j] * W1[j * 128 + c];
  hr[c] = fmaxf(acc, 0.f);
  __syncthreads();
  if (c < TD){
    float o = b2[c];
#pragma unroll 4
    for (int j = 0; j < 128; ++j) o += hr[j] * W2[j * TD + c];
    out[(size_t)g * TD + c] = o;
  }
}

extern "C" void kernel_launch(void* const* d_in, const int* in_sizes, int n_in,
                              void* d_out, int out_size, void* d_ws, size_t ws_size,
                              hipStream_t stream)
{
  const int*   atom_feat  = (const int*)  d_in[0];
  const int*   bond_feat  = (const int*)  d_in[1];
  const int*   edge_src   = (const int*)  d_in[2];
  const int*   edge_dst   = (const int*)  d_in[3];
  const int*   node2graph = (const int*)  d_in[4];
  const float* atom_emb   = (const float*)d_in[5];
  const float* bond_emb   = (const float*)d_in[6];
  const float* msg_W1     = (const float*)d_in[7];
  const float* msg_b1     = (const float*)d_in[8];
  const float* msg_W2     = (const float*)d_in[9];
  const float* msg_b2     = (const float*)d_in[10];
  const float* gate_W     = (const float*)d_in[11];
  const float* gate_b     = (const float*)d_in[12];
  const float* upd_W1     = (const float*)d_in[13];
  const float* upd_b1     = (const float*)d_in[14];
  const float* upd_W2     = (const float*)d_in[15];
  const float* upd_b2     = (const float*)d_in[16];
  const float* out_W1     = (const float*)d_in[17];
  const float* out_b1     = (const float*)d_in[18];
  const float* out_W2     = (const float*)d_in[19];
  const float* out_b2     = (const float*)d_in[20];
  const float* ro_W1      = (const float*)d_in[21];
  const float* ro_b1      = (const float*)d_in[22];
  const float* ro_W2      = (const float*)d_in[23];
  const float* ro_b2      = (const float*)d_in[24];
  (void)in_sizes; (void)n_in; (void)out_size; (void)ws_size;

  char* ws = (char*)d_ws;
  size_t off = 0;
  auto alloc = [&](size_t bytes) -> char* {
    char* p = ws + off;
    off = (off + bytes + 255) & ~(size_t)255;
    return p;
  };
  float*   h      = (float*)  alloc((size_t)NN * HD * 4);
  float*   hout   = (float*)  alloc((size_t)NN * HD * 4);
  ushort*  hbf    = (ushort*) alloc((size_t)NN * HD * 2);
  __half2* msum2  = (__half2*)alloc((size_t)NN * 64 * 4);
  ushort*  msgW1p = (ushort*) alloc((size_t)DEPTH * 384 * HD * 2);
  ushort*  msgW2p = (ushort*) alloc((size_t)DEPTH * HD * HD * 2); // f16
  ushort*  updW1p = (ushort*) alloc((size_t)DEPTH * HD * HD * 2);
  ushort*  updW2p = (ushort*) alloc((size_t)DEPTH * HD * HD * 2);
  ushort*  outW1p = (ushort*) alloc((size_t)HD * HD * 2);
  ushort*  outW2p = (ushort*) alloc((size_t)HD * HD * 2);
  ushort*  ebf    = (ushort*) alloc((size_t)512 * HD * 2);
  __half*  ecb    = (__half*) alloc((size_t)DEPTH * 512 * HD * 2);
  __half*  prea   = (__half*) alloc((size_t)NN * HD * 2);
  __half*  preb   = (__half*) alloc((size_t)NN * HD * 2);
  int*     deg    = (int*)    alloc((size_t)NN * 4);
  int*     head   = (int*)    alloc((size_t)NN * 4);
  int*     esrc_p = (int*)    alloc((size_t)NE * 4);
  int*     pc_p   = (int*)    alloc((size_t)NE * 4);

  pack6<<<dim3(48, 6), 256, 0, stream>>>(msg_W1, msg_W2, upd_W1, upd_W2, out_W1, out_W2,
                                         msgW1p, msgW2p, updW1p, updW2p, outW1p, outW2p);
  atom_encode<<<NN, HD, 0, stream>>>(atom_feat, atom_emb, h, hbf);
  ebf_k<<<512, HD, 0, stream>>>(bond_emb, ebf);
  ew1c_k<<<dim3(8, DEPTH), 256, 0, stream>>>(ebf, msgW1p, msg_b1, ecb);

  // counting sort of edges by dst
  zero_i<<<160, 256, 0, stream>>>(deg, NN);
  hist_k<<<640, 256, 0, stream>>>(edge_dst, deg);
  scan_head<<<1, 1024, 0, stream>>>(deg, head);
  scatter_k<<<640, 256, 0, stream>>>(edge_src, edge_dst, bond_feat, head,
                                     esrc_p, pc_p);

  for (int l = 0; l < DEPTH; ++l){
    pre_k<<<NN / 64, 256, 0, stream>>>(hbf, msgW1p + (size_t)l * 384 * HD, prea, preb,
                                       (uint*)msum2);
    msg2_kernel<<<NBLK2, 256, 0, stream>>>(
        prea, preb, ecb + (size_t)l * 512 * HD,
        esrc_p, pc_p,
        (const __half*)msgW2p + (size_t)l * HD * HD,
        msg_b2 + l * HD, gate_W + l * HD, gate_b + l, msum2);
    node_mlp<0><<<NN / 64, 256, 0, stream>>>(
        h, (const uint*)msum2,
        updW1p + (size_t)l * HD * HD, updW2p + (size_t)l * HD * HD,
        upd_b1 + l * HD, upd_b2 + l * HD, h, hbf);
  }
  node_mlp<1><<<NN / 64, 256, 0, stream>>>(
      h, nullptr, outW1p, outW2p, out_b1, out_b2, hout, nullptr);
  readout_final<<<NG, 128, 0, stream>>>(hout, node2graph, ro_W1, ro_b1, ro_W2, ro_b2,
                                        (float*)d_out);
}

// Round 15
// 681.319 us; speedup vs baseline: 1.3324x; 1.0397x over previous
//
#include <hip/hip_runtime.h>
#include <hip/hip_bf16.h>
#include <hip/hip_fp16.h>

#define NN 40000
#define NE 640000
#define HD 128
#define DEPTH 4
#define NG 1250
#define TD 32
#define AFN 9
#define AVN 64
#define BFN 3
#define BVN 8
#define NBLK2 (NE / 128)   // 5000, divisible by 8

typedef short bf16x8 __attribute__((ext_vector_type(8)));
typedef _Float16 f16x8 __attribute__((ext_vector_type(8)));
typedef _Float16 f16x2 __attribute__((ext_vector_type(2)));
typedef float f32x4 __attribute__((ext_vector_type(4)));

__device__ __forceinline__ uint cvtpk(float lo, float hi){
  uint r; asm("v_cvt_pk_bf16_f32 %0, %1, %2" : "=v"(r) : "v"(lo), "v"(hi)); return r;
}
__device__ __forceinline__ ushort f2bf(float x){ return (ushort)cvtpk(x, x); }
__device__ __forceinline__ float rcpfa(float x){ return __builtin_amdgcn_rcpf(x); }
__device__ __forceinline__ float siluf(float x){ return x * rcpfa(1.f + __expf(-x)); }
__device__ __forceinline__ float sigmf(float x){ return rcpfa(1.f + __expf(-x)); }
__device__ __forceinline__ uint packbf2(float a, float b){ return cvtpk(a, b); }

__device__ __forceinline__ __half2 silu_h2(__half2 x){
  const __half2 nl2e = __float2half2_rn(-1.44269504f);
  const __half2 one  = __float2half2_rn(1.f);
  __half2 e = h2exp2(__hmul2(x, nl2e));
  return __hmul2(x, h2rcp(__hadd2(one, e)));
}
union H2U { __half2 h; f16x2 v; uint u; };
__device__ __forceinline__ __half2 pkrtz(float lo, float hi){
  auto t = __builtin_amdgcn_cvt_pkrtz(lo, hi);
  H2U r; __builtin_memcpy(&r.u, &t, 4); return r.h;
}

// ---------------- pack all weights in one launch ----------------
__device__ __forceinline__ void pack_one(const float* __restrict__ src,
                                         ushort* __restrict__ dst,
                                         int K, int L, int isf16){
  int total = L * K * HD;
  for (int idx = blockIdx.x * blockDim.x + threadIdx.x; idx < total;
       idx += gridDim.x * blockDim.x){
    int l = idx / (K * HD);
    int r = idx - l * K * HD;
    int k = r / HD;
    int n = r - k * HD;
    float v = src[idx];
    ushort o;
    if (isf16){ __half hv = __float2half_rn(v); o = *(ushort*)&hv; }
    else o = f2bf(v);
    dst[(size_t)l * K * HD + ((size_t)(k >> 3) * HD + n) * 8 + (k & 7)] = o;
  }
}
__global__ void pack6(const float* s0, const float* s1, const float* s2,
                      const float* s3, const float* s4, const float* s5,
                      ushort* d0, ushort* d1, ushort* d2,
                      ushort* d3, ushort* d4, ushort* d5){
  switch (blockIdx.y){
    case 0: pack_one(s0, d0, 384, DEPTH, 0); break;
    case 1: pack_one(s1, d1, HD, DEPTH, 1); break;
    case 2: pack_one(s2, d2, HD, DEPTH, 0); break;
    case 3: pack_one(s3, d3, HD, DEPTH, 0); break;
    case 4: pack_one(s4, d4, HD, 1, 0); break;
    default: pack_one(s5, d5, HD, 1, 0); break;
  }
}

__global__ void zero_i(int* __restrict__ p, int n){
  for (int i = blockIdx.x * blockDim.x + threadIdx.x; i < n; i += gridDim.x * blockDim.x)
    p[i] = 0;
}

// ---------------- atom encoder ----------------
__global__ void atom_encode(const int* __restrict__ feat, const float* __restrict__ emb,
                            float* __restrict__ h, ushort* __restrict__ hbf){
  int n = blockIdx.x;
  int c = threadIdx.x; // 128
  float acc = 0.f;
#pragma unroll
  for (int f = 0; f < AFN; ++f){
    int v = feat[n * AFN + f];
    acc += emb[(size_t)(f * AVN + v) * HD + c];
  }
  h[(size_t)n * HD + c] = acc;
  hbf[(size_t)n * HD + c] = f2bf(acc);
}

// ---------------- bond combo table: ebf[512][128] bf16 ----------------
__global__ void ebf_k(const float* __restrict__ bemb, ushort* __restrict__ ebf){
  const int cid = blockIdx.x;      // 512
  const int c = threadIdx.x;       // 128
  const int f0 = cid >> 6, f1 = (cid >> 3) & 7, f2 = cid & 7;
  float v = bemb[(size_t)(0 * BVN + f0) * HD + c]
          + bemb[(size_t)(1 * BVN + f1) * HD + c]
          + bemb[(size_t)(2 * BVN + f2) * HD + c];
  ebf[(size_t)cid * HD + c] = f2bf(v);
}

// ---------------- edge histogram by dst ----------------
__global__ void hist_k(const int* __restrict__ edst, int* __restrict__ deg){
  for (int e = blockIdx.x * blockDim.x + threadIdx.x; e < NE; e += gridDim.x * blockDim.x)
    atomicAdd(&deg[edst[e]], 1);
}

// ---------------- exclusive scan over NN=40000 (single block, 1024 thr) ----------------
__global__ __launch_bounds__(1024) void scan_head(const int* __restrict__ deg,
                                                  int* __restrict__ head){
  __shared__ int buf[1024];
  const int t = threadIdx.x;
  const int base = t * 40;
  int s = 0;
  int dloc[40];
  if (t < 1000){
#pragma unroll
    for (int i = 0; i < 40; ++i){ dloc[i] = deg[base + i]; s += dloc[i]; }
  }
  buf[t] = s;
  __syncthreads();
  for (int ofs = 1; ofs < 1024; ofs <<= 1){
    int x = (t >= ofs) ? buf[t - ofs] : 0;
    __syncthreads();
    buf[t] += x;
    __syncthreads();
  }
  if (t < 1000){
    int run = buf[t] - s;
#pragma unroll
    for (int i = 0; i < 40; ++i){ head[base + i] = run; run += dloc[i]; }
  }
}

// ---------------- scatter edges into dst-sorted order ----------------
__global__ void scatter_k(const int* __restrict__ esrc, const int* __restrict__ edst,
                          const int* __restrict__ bfeat, int* __restrict__ head,
                          int* __restrict__ esrc_p, int* __restrict__ dst_p,
                          int* __restrict__ cid_p){
  for (int e = blockIdx.x * blockDim.x + threadIdx.x; e < NE; e += gridDim.x * blockDim.x){
    const int d = edst[e];
    const int pos = atomicAdd(&head[d], 1);
    esrc_p[pos] = esrc[e];
    dst_p[pos] = d;
    cid_p[pos] = bfeat[e * 3 + 0] * 64 + bfeat[e * 3 + 1] * 8 + bfeat[e * 3 + 2];
  }
}

// ---------------- per-layer node precompute: prea/preb = hbf@W1a/b (f16) + zero msum ----------------
__global__ __launch_bounds__(256) void pre_k(
    const ushort* __restrict__ hbf, const ushort* __restrict__ W1p,
    __half* __restrict__ prea, __half* __restrict__ preb,
    uint* __restrict__ msum2)
{
  const int tid = threadIdx.x;
  const int n0 = blockIdx.x * 64;
  { // zero this block's msum2 rows (64 nodes x 64 pairs = 1024 uint4)
    uint4* mz = (uint4*)(msum2 + (size_t)n0 * 64);
    const uint4 z = make_uint4(0u, 0u, 0u, 0u);
#pragma unroll
    for (int i = 0; i < 4; ++i) mz[tid + i * 256] = z;
  }
  const int lane = tid & 63, wv = tid >> 6;
  const int lr = lane & 15, lg = lane >> 4;
  const int arow = n0 + wv * 16 + lr;
  bf16x8 a[4];
#pragma unroll
  for (int ks = 0; ks < 4; ++ks)
    a[ks] = *(const bf16x8*)(hbf + (size_t)arow * HD + ks * 32 + lg * 8);
  const f32x4 zero = {0.f, 0.f, 0.f, 0.f};
  f32x4 acc[16];
#pragma unroll
  for (int i = 0; i < 16; ++i) acc[i] = zero;
#pragma unroll
  for (int ks = 0; ks < 4; ++ks){
#pragma unroll
    for (int ct = 0; ct < 16; ++ct){
      const int oct = ks * 4 + lg + ((ct >= 8) ? 16 : 0);
      const int ncol = (ct & 7) * 16 + lr;
      bf16x8 b = *(const bf16x8*)(W1p + ((size_t)oct * HD + ncol) * 8);
      acc[ct] = __builtin_amdgcn_mfma_f32_16x16x32_bf16(a[ks], b, acc[ct], 0, 0, 0);
    }
  }
#pragma unroll
  for (int ct = 0; ct < 16; ++ct){
    __half* dstp = (ct < 8) ? prea : preb;
    const int ncol = (ct & 7) * 16 + lr;
#pragma unroll
    for (int r = 0; r < 4; ++r){
      const int nrow = n0 + wv * 16 + lg * 4 + r;
      dstp[(size_t)nrow * HD + ncol] = __float2half_rn(acc[ct][r]);
    }
  }
}

// ---------------- per-layer bond-combo contribution: ecb = ebf@W1c + b1 (f16) ----------------
__global__ __launch_bounds__(256) void ew1c_k(
    const ushort* __restrict__ ebf, const ushort* __restrict__ W1p_all,
    const float* __restrict__ b1_all, __half* __restrict__ ecb_all)
{
  const int l = blockIdx.y;
  const ushort* W1p = W1p_all + (size_t)l * 384 * HD;
  const float* b1v = b1_all + l * HD;
  __half* ecb = ecb_all + (size_t)l * 512 * HD;
  const int tid = threadIdx.x;
  const int c0 = blockIdx.x * 64;
  const int lane = tid & 63, wv = tid >> 6;
  const int lr = lane & 15, lg = lane >> 4;
  const int arow = c0 + wv * 16 + lr;
  bf16x8 a[4];
#pragma unroll
  for (int ks = 0; ks < 4; ++ks)
    a[ks] = *(const bf16x8*)(ebf + (size_t)arow * HD + ks * 32 + lg * 8);
  const f32x4 zero = {0.f, 0.f, 0.f, 0.f};
  f32x4 acc[8];
#pragma unroll
  for (int i = 0; i < 8; ++i) acc[i] = zero;
#pragma unroll
  for (int ks = 0; ks < 4; ++ks){
#pragma unroll
    for (int ct = 0; ct < 8; ++ct){
      const int oct = ks * 4 + lg + 32;
      const int ncol = ct * 16 + lr;
      bf16x8 b = *(const bf16x8*)(W1p + ((size_t)oct * HD + ncol) * 8);
      acc[ct] = __builtin_amdgcn_mfma_f32_16x16x32_bf16(a[ks], b, acc[ct], 0, 0, 0);
    }
  }
#pragma unroll
  for (int ct = 0; ct < 8; ++ct){
    const int ncol = ct * 16 + lr;
    const float bias = b1v[ncol];
#pragma unroll
    for (int r = 0; r < 4; ++r){
      const int nrow = c0 + wv * 16 + lg * 4 + r;
      ecb[(size_t)nrow * HD + ncol] = __float2half_rn(acc[ct][r] + bias);
    }
  }
}

// ---------------- fused edge kernel: 128 edges/block, 2 tiles/wave sharing B ----------------
// issue-early: per ks-step, all 6 gather loads (both tiles) before any silu math
__device__ __forceinline__ void build_af2(
    const __half* __restrict__ prea, const __half* __restrict__ preb,
    const __half* __restrict__ ecb,
    int s0, int d0, int c0, int s1, int d1, int c1, int lg,
    f16x8* af0, f16x8* af1)
{
#pragma unroll
  for (int ks = 0; ks < 4; ++ks){
    const int off = ks * 32 + lg * 8;
    union { uint4 q; __half2 h[4]; f16x8 v; } ua0, ub0, uc0, uo0, ua1, ub1, uc1, uo1;
    ua0.q = *(const uint4*)(prea + (size_t)s0 * HD + off);
    ub0.q = *(const uint4*)(preb + (size_t)d0 * HD + off);
    uc0.q = *(const uint4*)(ecb + (size_t)c0 * HD + off);
    ua1.q = *(const uint4*)(prea + (size_t)s1 * HD + off);
    ub1.q = *(const uint4*)(preb + (size_t)d1 * HD + off);
    uc1.q = *(const uint4*)(ecb + (size_t)c1 * HD + off);
#pragma unroll
    for (int j = 0; j < 4; ++j){
      uo0.h[j] = silu_h2(__hadd2(__hadd2(ua0.h[j], ub0.h[j]), uc0.h[j]));
      uo1.h[j] = silu_h2(__hadd2(__hadd2(ua1.h[j], ub1.h[j]), uc1.h[j]));
    }
    af0[ks] = uo0.v;
    af1[ks] = uo1.v;
  }
}

__device__ __forceinline__ void edge_epilogue(
    f32x4* acc, int lr, int lg, int rowbase,
    const float* b2l, const float* b2h, const __half2* gwh, float gbias,
    uint* Ms)
{
  __half2 mh[4][4];
#pragma unroll
  for (int ct = 0; ct < 4; ++ct){
#pragma unroll
    for (int r = 0; r < 4; ++r)
      mh[ct][r] = silu_h2(pkrtz(acc[ct][r] + b2l[ct], acc[ct + 4][r] + b2h[ct]));
  }
#pragma unroll
  for (int r = 0; r < 4; ++r){
    float sgs = 0.f;
#pragma unroll
    for (int ct = 0; ct < 4; ++ct){
      H2U a, b; a.h = mh[ct][r]; b.h = gwh[ct];
      sgs = __builtin_amdgcn_fdot2(a.v, b.v, sgs, false);
    }
    sgs += __shfl_xor(sgs, 1); sgs += __shfl_xor(sgs, 2);
    sgs += __shfl_xor(sgs, 4); sgs += __shfl_xor(sgs, 8);
    const __half2 gh = __float2half2_rn(sigmf(sgs + gbias));
#pragma unroll
    for (int ct = 0; ct < 4; ++ct) mh[ct][r] = __hmul2(mh[ct][r], gh);
  }
#pragma unroll
  for (int ct = 0; ct < 4; ++ct){
    const int ui = ct * 16 + lr;
#pragma unroll
    for (int r = 0; r < 4; ++r){
      const int lrow = rowbase + lg * 4 + r;
      H2U w; w.h = mh[ct][r];
      *(uint*)((char*)Ms + lrow * 256 + (((uint)(ui * 4)) ^ ((uint)((lrow & 7) << 4)))) = w.u;
    }
  }
}

__global__ __launch_bounds__(256, 4) void msg2_kernel(
    const __half* __restrict__ prea, const __half* __restrict__ preb,
    const __half* __restrict__ ecb,
    const int* __restrict__ esrc_p, const int* __restrict__ dst_p,
    const int* __restrict__ cid_p,
    const __half* __restrict__ W2p, const float* __restrict__ b2v,
    const float* __restrict__ gw, const float* __restrict__ gb,
    __half2* __restrict__ msum2)
{
  __shared__ uint Ms[128 * 64]; // parked m pairs for 128 edges; row stride 256B, swizzled
  __shared__ int dsh[128];
  const int tid = threadIdx.x;
  // chunked XCD swizzle (bijective: NBLK2 % 8 == 0)
  const int bid = (int)blockIdx.x;
  const int bsw = (bid & 7) * (NBLK2 >> 3) + (bid >> 3);
  const int e0 = bsw * 128;
  if (tid < 128) dsh[tid] = dst_p[e0 + tid];

  const int lane = tid & 63;
  const int wv = tid >> 6;
  const int lr = lane & 15, lg = lane >> 4;
  const int row0 = e0 + wv * 16 + lr;       // tile 0 edge row
  const int row1 = row0 + 64;               // tile 1 edge row
  const int s0 = esrc_p[row0], d0 = dst_p[row0], c0 = cid_p[row0];
  const int s1 = esrc_p[row1], d1 = dst_p[row1], c1 = cid_p[row1];

  f16x8 af0[4], af1[4];
  build_af2(prea, preb, ecb, s0, d0, c0, s1, d1, c1, lg, af0, af1);

  // GEMM2 for both tiles, one B-load per (ks,ct)
  const f32x4 zero = {0.f, 0.f, 0.f, 0.f};
  f32x4 acc0[8], acc1[8];
#pragma unroll
  for (int i = 0; i < 8; ++i){ acc0[i] = zero; acc1[i] = zero; }
#pragma unroll
  for (int ks = 0; ks < 4; ++ks){
    const __half* wb = W2p + ((size_t)(ks * 4 + lg) * HD + lr) * 8;
#pragma unroll
    for (int ct = 0; ct < 8; ++ct){
      f16x8 b = *(const f16x8*)(wb + ct * 16 * 8);
      acc0[ct] = __builtin_amdgcn_mfma_f32_16x16x32_f16(af0[ks], b, acc0[ct], 0, 0, 0);
      acc1[ct] = __builtin_amdgcn_mfma_f32_16x16x32_f16(af1[ks], b, acc1[ct], 0, 0, 0);
    }
  }

  float b2l[4], b2h[4];
  __half2 gwh[4];
#pragma unroll
  for (int ct = 0; ct < 4; ++ct){
    b2l[ct] = b2v[ct * 16 + lr];
    b2h[ct] = b2v[ct * 16 + lr + 64];
    gwh[ct] = pkrtz(gw[ct * 16 + lr], gw[ct * 16 + lr + 64]);
  }
  const float gbias = gb[0];
  edge_epilogue(acc0, lr, lg, wv * 16, b2l, b2h, gwh, gbias, Ms);
  edge_epilogue(acc1, lr, lg, 64 + wv * 16, b2l, b2h, gwh, gbias, Ms);
  __syncthreads();

  // segmented reduction: 64 col-pairs x 4 row-segments of 32; one packed-f16 atomic per run
  {
    const int cp = tid & 63;
    const int seg = tid >> 6;
    const int r0 = seg * 32, r1 = r0 + 32;
    float rl = 0.f, rh = 0.f;
    int cur = dsh[r0];
    for (int r = r0; r < r1; ++r){
      const int dd = dsh[r];
      if (dd != cur){
        unsafeAtomicAdd(&msum2[(size_t)cur * 64 + cp], pkrtz(rl, rh));
        rl = 0.f; rh = 0.f; cur = dd;
      }
      H2U w;
      w.u = *(const uint*)((const char*)Ms + r * 256 +
                           (((uint)(cp * 4)) ^ ((uint)((r & 7) << 4))));
      rl += __low2float(w.h); rh += __high2float(w.h);
    }
    unsafeAtomicAdd(&msum2[(size_t)cur * 64 + cp], pkrtz(rl, rh));
  }
}

// ---------------- fused node MLP (64 nodes/block) ----------------
// MODE 0: A = bf16(h + msum); out = silu(A@W1+b1)@W2 + b2 + h -> h, hbf
// MODE 1: A = bf16(h);        out = silu(A@W1+b1)@W2 + b2     -> outp
template <int MODE>
__global__ __launch_bounds__(256) void node_mlp(
    const float* hin, const uint* __restrict__ msum2,
    const ushort* __restrict__ W1p, const ushort* __restrict__ W2p,
    const float* __restrict__ b1v, const float* __restrict__ b2v,
    float* outp, ushort* __restrict__ hbf)
{
  __shared__ ushort At[64 * 128];
  __shared__ ushort Tt[64 * 128];
  const int tid = threadIdx.x;
  const int n0 = blockIdx.x * 64;

  { // stage: 4 threads per node, 32 cols each
    const int nl = tid >> 2, part = tid & 3;
    const int node = n0 + nl;
    const float4* hp = (const float4*)(hin + (size_t)node * HD + part * 32);
    const uint* mp = (MODE == 0) ? (msum2 + (size_t)node * 64) : nullptr;
    const bool hiHalf = (MODE == 0) && (part >= 2);
    char* rowp = (char*)At + nl * 256;
    const uint sw = (uint)((nl & 7) << 4);
#pragma unroll
    for (int j = 0; j < 4; ++j){
      float4 x0 = hp[j * 2 + 0], x1 = hp[j * 2 + 1];
      if (MODE == 0){
        const int cp0 = (part & 1) * 32 + j * 8;
        uint4 ma = *(const uint4*)(mp + cp0);
        uint4 mb = *(const uint4*)(mp + cp0 + 4);
        H2U w0, w1, w2, w3, w4, w5, w6, w7;
        w0.u = ma.x; w1.u = ma.y; w2.u = ma.z; w3.u = ma.w;
        w4.u = mb.x; w5.u = mb.y; w6.u = mb.z; w7.u = mb.w;
        if (hiHalf){
          x0.x += __high2float(w0.h); x0.y += __high2float(w1.h);
          x0.z += __high2float(w2.h); x0.w += __high2float(w3.h);
          x1.x += __high2float(w4.h); x1.y += __high2float(w5.h);
          x1.z += __high2float(w6.h); x1.w += __high2float(w7.h);
        } else {
          x0.x += __low2float(w0.h); x0.y += __low2float(w1.h);
          x0.z += __low2float(w2.h); x0.w += __low2float(w3.h);
          x1.x += __low2float(w4.h); x1.y += __low2float(w5.h);
          x1.z += __low2float(w6.h); x1.w += __low2float(w7.h);
        }
      }
      uint4 o;
      o.x = packbf2(x0.x, x0.y); o.y = packbf2(x0.z, x0.w);
      o.z = packbf2(x1.x, x1.y); o.w = packbf2(x1.z, x1.w);
      uint cb = (uint)(part * 64 + j * 16);
      *(uint4*)(rowp + (cb ^ sw)) = o;
    }
  }
  __syncthreads();

  const int lane = tid & 63;
  const int wv = tid >> 6;
  const int lr = lane & 15, lg = lane >> 4;
  const int rowbase = wv * 16;
  const f32x4 zero = {0.f, 0.f, 0.f, 0.f};
  const int arow = rowbase + lr;
  const char* arp = (const char*)At + arow * 256;
  const uint asw = (uint)((arow & 7) << 4);

  f32x4 acc[8];
#pragma unroll
  for (int i = 0; i < 8; ++i) acc[i] = zero;
#pragma unroll
  for (int ks = 0; ks < 4; ++ks){
    uint cb = (uint)(ks * 64 + lg * 16);
    bf16x8 a = *(const bf16x8*)(arp + (cb ^ asw));
    const ushort* wbase = W1p + ((size_t)(ks * 4 + lg) * 128 + lr) * 8;
#pragma unroll
    for (int ct = 0; ct < 8; ++ct){
      bf16x8 b = *(const bf16x8*)(wbase + ct * 16 * 8);
      acc[ct] = __builtin_amdgcn_mfma_f32_16x16x32_bf16(a, b, acc[ct], 0, 0, 0);
    }
  }
#pragma unroll
  for (int ct = 0; ct < 8; ++ct){
    const int col = ct * 16 + lr;
    const float bias = b1v[col];
#pragma unroll
    for (int r = 0; r < 4; ++r){
      const int row = rowbase + lg * 4 + r;
      float v = siluf(acc[ct][r] + bias);
      *(ushort*)((char*)Tt + row * 256 + (((uint)(col * 2)) ^ ((uint)(row & 7) << 4))) = f2bf(v);
    }
  }
  __syncthreads();

  f32x4 acc2[8];
#pragma unroll
  for (int i = 0; i < 8; ++i) acc2[i] = zero;
  {
    const char* trp = (const char*)Tt + arow * 256;
#pragma unroll
    for (int ks = 0; ks < 4; ++ks){
      uint cb = (uint)(ks * 64 + lg * 16);
      bf16x8 a = *(const bf16x8*)(trp + (cb ^ asw));
      const ushort* wbase = W2p + ((size_t)(ks * 4 + lg) * 128 + lr) * 8;
#pragma unroll
      for (int ct = 0; ct < 8; ++ct){
        bf16x8 b = *(const bf16x8*)(wbase + ct * 16 * 8);
        acc2[ct] = __builtin_amdgcn_mfma_f32_16x16x32_bf16(a, b, acc2[ct], 0, 0, 0);
      }
    }
  }
#pragma unroll
  for (int ct = 0; ct < 8; ++ct){
    const int col = ct * 16 + lr;
    const float bias = b2v[col];
#pragma unroll
    for (int r = 0; r < 4; ++r){
      const int node = n0 + rowbase + lg * 4 + r;
      float v = acc2[ct][r] + bias;
      if (MODE == 0) v += hin[(size_t)node * HD + col];
      outp[(size_t)node * HD + col] = v;
      if (MODE == 0) hbf[(size_t)node * HD + col] = f2bf(v);
    }
  }
}

// ---------------- fused per-graph readout + final MLP ----------------
__global__ __launch_bounds__(128) void readout_final(
    const float* __restrict__ hout, const int* __restrict__ n2g,
    const float* __restrict__ W1, const float* __restrict__ b1,
    const float* __restrict__ W2, const float* __restrict__ b2,
    float* __restrict__ out){
  __shared__ float rsh[384];
  __shared__ float hr[128];
  const int g = blockIdx.x;
  const int c = threadIdx.x; // 128
  int lo, hi;
  { int a = 0, b = NN; while (a < b){ int mid = (a + b) >> 1; if (n2g[mid] < g) a = mid + 1; else b = mid; } lo = a; }
  { int a = lo, b = NN; while (a < b){ int mid = (a + b) >> 1; if (n2g[mid] < g + 1) a = mid + 1; else b = mid; } hi = a; }
  float s = 0.f, mx = -3.4e38f;
  for (int n = lo; n < hi; ++n){
    float v = hout[(size_t)n * HD + c];
    s += v; mx = fmaxf(mx, v);
  }
  const int cnt = hi - lo;
  float mean = (cnt > 0) ? s / (float)cnt : 0.f;
  if (cnt == 0){ s = 0.f; mx = 0.f; }
  rsh[c] = s; rsh[128 + c] = mean; rsh[256 + c] = mx;
  __syncthreads();
  float acc = b1[c];
#pragma unroll 4
  for (int j = 0; j < 384; ++j) acc += rsh[j] * W1[j * 128 + c];
  hr[c] = fmaxf(acc, 0.f);
  __syncthreads();
  if (c < TD){
    float o = b2[c];
#pragma unroll 4
    for (int j = 0; j < 128; ++j) o += hr[j] * W2[j * TD + c];
    out[(size_t)g * TD + c] = o;
  }
}

extern "C" void kernel_launch(void* const* d_in, const int* in_sizes, int n_in,
                              void* d_out, int out_size, void* d_ws, size_t ws_size,
                              hipStream_t stream)
{
  const int*   atom_feat  = (const int*)  d_in[0];
  const int*   bond_feat  = (const int*)  d_in[1];
  const int*   edge_src   = (const int*)  d_in[2];
  const int*   edge_dst   = (const int*)  d_in[3];
  const int*   node2graph = (const int*)  d_in[4];
  const float* atom_emb   = (const float*)d_in[5];
  const float* bond_emb   = (const float*)d_in[6];
  const float* msg_W1     = (const float*)d_in[7];
  const float* msg_b1     = (const float*)d_in[8];
  const float* msg_W2     = (const float*)d_in[9];
  const float* msg_b2     = (const float*)d_in[10];
  const float* gate_W     = (const float*)d_in[11];
  const float* gate_b     = (const float*)d_in[12];
  const float* upd_W1     = (const float*)d_in[13];
  const float* upd_b1     = (const float*)d_in[14];
  const float* upd_W2     = (const float*)d_in[15];
  const float* upd_b2     = (const float*)d_in[16];
  const float* out_W1     = (const float*)d_in[17];
  const float* out_b1     = (const float*)d_in[18];
  const float* out_W2     = (const float*)d_in[19];
  const float* out_b2     = (const float*)d_in[20];
  const float* ro_W1      = (const float*)d_in[21];
  const float* ro_b1      = (const float*)d_in[22];
  const float* ro_W2      = (const float*)d_in[23];
  const float* ro_b2      = (const float*)d_in[24];
  (void)in_sizes; (void)n_in; (void)out_size; (void)ws_size;

  char* ws = (char*)d_ws;
  size_t off = 0;
  auto alloc = [&](size_t bytes) -> char* {
    char* p = ws + off;
    off = (off + bytes + 255) & ~(size_t)255;
    return p;
  };
  float*   h      = (float*)  alloc((size_t)NN * HD * 4);
  float*   hout   = (float*)  alloc((size_t)NN * HD * 4);
  ushort*  hbf    = (ushort*) alloc((size_t)NN * HD * 2);
  __half2* msum2  = (__half2*)alloc((size_t)NN * 64 * 4);
  ushort*  msgW1p = (ushort*) alloc((size_t)DEPTH * 384 * HD * 2);
  ushort*  msgW2p = (ushort*) alloc((size_t)DEPTH * HD * HD * 2); // f16
  ushort*  updW1p = (ushort*) alloc((size_t)DEPTH * HD * HD * 2);
  ushort*  updW2p = (ushort*) alloc((size_t)DEPTH * HD * HD * 2);
  ushort*  outW1p = (ushort*) alloc((size_t)HD * HD * 2);
  ushort*  outW2p = (ushort*) alloc((size_t)HD * HD * 2);
  ushort*  ebf    = (ushort*) alloc((size_t)512 * HD * 2);
  __half*  ecb    = (__half*) alloc((size_t)DEPTH * 512 * HD * 2);
  __half*  prea   = (__half*) alloc((size_t)NN * HD * 2);
  __half*  preb   = (__half*) alloc((size_t)NN * HD * 2);
  int*     deg    = (int*)    alloc((size_t)NN * 4);
  int*     head   = (int*)    alloc((size_t)NN * 4);
  int*     esrc_p = (int*)    alloc((size_t)NE * 4);
  int*     dst_p  = (int*)    alloc((size_t)NE * 4);
  int*     cid_p  = (int*)    alloc((size_t)NE * 4);

  pack6<<<dim3(48, 6), 256, 0, stream>>>(msg_W1, msg_W2, upd_W1, upd_W2, out_W1, out_W2,
                                         msgW1p, msgW2p, updW1p, updW2p, outW1p, outW2p);
  atom_encode<<<NN, HD, 0, stream>>>(atom_feat, atom_emb, h, hbf);
  ebf_k<<<512, HD, 0, stream>>>(bond_emb, ebf);
  ew1c_k<<<dim3(8, DEPTH), 256, 0, stream>>>(ebf, msgW1p, msg_b1, ecb);

  // counting sort of edges by dst
  zero_i<<<160, 256, 0, stream>>>(deg, NN);
  hist_k<<<640, 256, 0, stream>>>(edge_dst, deg);
  scan_head<<<1, 1024, 0, stream>>>(deg, head);
  scatter_k<<<640, 256, 0, stream>>>(edge_src, edge_dst, bond_feat, head,
                                     esrc_p, dst_p, cid_p);

  for (int l = 0; l < DEPTH; ++l){
    pre_k<<<NN / 64, 256, 0, stream>>>(hbf, msgW1p + (size_t)l * 384 * HD, prea, preb,
                                       (uint*)msum2);
    msg2_kernel<<<NBLK2, 256, 0, stream>>>(
        prea, preb, ecb + (size_t)l * 512 * HD,
        esrc_p, dst_p, cid_p,
        (const __half*)msgW2p + (size_t)l * HD * HD,
        msg_b2 + l * HD, gate_W + l * HD, gate_b + l, msum2);
    node_mlp<0><<<NN / 64, 256, 0, stream>>>(
        h, (const uint*)msum2,
        updW1p + (size_t)l * HD * HD, updW2p + (size_t)l * HD * HD,
        upd_b1 + l * HD, upd_b2 + l * HD, h, hbf);
  }
  node_mlp<1><<<NN / 64, 256, 0, stream>>>(
      h, nullptr, outW1p, outW2p, out_b1, out_b2, hout, nullptr);
  readout_final<<<NG, 128, 0, stream>>>(hout, node2graph, ro_W1, ro_b1, ro_W2, ro_b2,
                                        (float*)d_out);
}

// Round 16
// 675.040 us; speedup vs baseline: 1.3448x; 1.0093x over previous
//
#include <hip/hip_runtime.h>
#include <hip/hip_bf16.h>
#include <hip/hip_fp16.h>

#define NN 40000
#define NE 640000
#define HD 128
#define DEPTH 4
#define NG 1250
#define TD 32
#define AFN 9
#define AVN 64
#define BFN 3
#define BVN 8
#define NBLK2 (NE / 128)   // 5000, divisible by 8

typedef short bf16x8 __attribute__((ext_vector_type(8)));
typedef _Float16 f16x8 __attribute__((ext_vector_type(8)));
typedef _Float16 f16x2 __attribute__((ext_vector_type(2)));
typedef float f32x4 __attribute__((ext_vector_type(4)));

__device__ __forceinline__ uint cvtpk(float lo, float hi){
  uint r; asm("v_cvt_pk_bf16_f32 %0, %1, %2" : "=v"(r) : "v"(lo), "v"(hi)); return r;
}
__device__ __forceinline__ ushort f2bf(float x){ return (ushort)cvtpk(x, x); }
__device__ __forceinline__ float rcpfa(float x){ return __builtin_amdgcn_rcpf(x); }
__device__ __forceinline__ float siluf(float x){ return x * rcpfa(1.f + __expf(-x)); }
__device__ __forceinline__ float sigmf(float x){ return rcpfa(1.f + __expf(-x)); }
__device__ __forceinline__ uint packbf2(float a, float b){ return cvtpk(a, b); }

__device__ __forceinline__ __half2 silu_h2(__half2 x){
  const __half2 nl2e = __float2half2_rn(-1.44269504f);
  const __half2 one  = __float2half2_rn(1.f);
  __half2 e = h2exp2(__hmul2(x, nl2e));
  return __hmul2(x, h2rcp(__hadd2(one, e)));
}
union H2U { __half2 h; f16x2 v; uint u; };
__device__ __forceinline__ __half2 pkrtz(float lo, float hi){
  auto t = __builtin_amdgcn_cvt_pkrtz(lo, hi);
  H2U r; __builtin_memcpy(&r.u, &t, 4); return r.h;
}

// ---------------- pack all weights in one launch ----------------
__device__ __forceinline__ void pack_one(const float* __restrict__ src,
                                         ushort* __restrict__ dst,
                                         int K, int L, int isf16){
  int total = L * K * HD;
  for (int idx = blockIdx.x * blockDim.x + threadIdx.x; idx < total;
       idx += gridDim.x * blockDim.x){
    int l = idx / (K * HD);
    int r = idx - l * K * HD;
    int k = r / HD;
    int n = r - k * HD;
    float v = src[idx];
    ushort o;
    if (isf16){ __half hv = __float2half_rn(v); o = *(ushort*)&hv; }
    else o = f2bf(v);
    dst[(size_t)l * K * HD + ((size_t)(k >> 3) * HD + n) * 8 + (k & 7)] = o;
  }
}
__global__ void pack6(const float* s0, const float* s1, const float* s2,
                      const float* s3, const float* s4, const float* s5,
                      ushort* d0, ushort* d1, ushort* d2,
                      ushort* d3, ushort* d4, ushort* d5){
  switch (blockIdx.y){
    case 0: pack_one(s0, d0, 384, DEPTH, 0); break;
    case 1: pack_one(s1, d1, HD, DEPTH, 1); break;
    case 2: pack_one(s2, d2, HD, DEPTH, 0); break;
    case 3: pack_one(s3, d3, HD, DEPTH, 0); break;
    case 4: pack_one(s4, d4, HD, 1, 0); break;
    default: pack_one(s5, d5, HD, 1, 0); break;
  }
}

__global__ void zero_i(int* __restrict__ p, int n){
  for (int i = blockIdx.x * blockDim.x + threadIdx.x; i < n; i += gridDim.x * blockDim.x)
    p[i] = 0;
}

// ---------------- atom encoder ----------------
__global__ void atom_encode(const int* __restrict__ feat, const float* __restrict__ emb,
                            float* __restrict__ h, ushort* __restrict__ hbf){
  int n = blockIdx.x;
  int c = threadIdx.x; // 128
  float acc = 0.f;
#pragma unroll
  for (int f = 0; f < AFN; ++f){
    int v = feat[n * AFN + f];
    acc += emb[(size_t)(f * AVN + v) * HD + c];
  }
  h[(size_t)n * HD + c] = acc;
  hbf[(size_t)n * HD + c] = f2bf(acc);
}

// ---------------- bond combo table: ebf[512][128] bf16 ----------------
__global__ void ebf_k(const float* __restrict__ bemb, ushort* __restrict__ ebf){
  const int cid = blockIdx.x;      // 512
  const int c = threadIdx.x;       // 128
  const int f0 = cid >> 6, f1 = (cid >> 3) & 7, f2 = cid & 7;
  float v = bemb[(size_t)(0 * BVN + f0) * HD + c]
          + bemb[(size_t)(1 * BVN + f1) * HD + c]
          + bemb[(size_t)(2 * BVN + f2) * HD + c];
  ebf[(size_t)cid * HD + c] = f2bf(v);
}

// ---------------- edge histogram by dst ----------------
__global__ void hist_k(const int* __restrict__ edst, int* __restrict__ deg){
  for (int e = blockIdx.x * blockDim.x + threadIdx.x; e < NE; e += gridDim.x * blockDim.x)
    atomicAdd(&deg[edst[e]], 1);
}

// ---------------- exclusive scan over NN=40000 (single block, 1024 thr) ----------------
__global__ __launch_bounds__(1024) void scan_head(const int* __restrict__ deg,
                                                  int* __restrict__ head){
  __shared__ int buf[1024];
  const int t = threadIdx.x;
  const int base = t * 40;
  int s = 0;
  int dloc[40];
  if (t < 1000){
#pragma unroll
    for (int i = 0; i < 40; ++i){ dloc[i] = deg[base + i]; s += dloc[i]; }
  }
  buf[t] = s;
  __syncthreads();
  for (int ofs = 1; ofs < 1024; ofs <<= 1){
    int x = (t >= ofs) ? buf[t - ofs] : 0;
    __syncthreads();
    buf[t] += x;
    __syncthreads();
  }
  if (t < 1000){
    int run = buf[t] - s;
#pragma unroll
    for (int i = 0; i < 40; ++i){ head[base + i] = run; run += dloc[i]; }
  }
}

// ---------------- scatter edges into dst-sorted order ----------------
__global__ void scatter_k(const int* __restrict__ esrc, const int* __restrict__ edst,
                          const int* __restrict__ bfeat, int* __restrict__ head,
                          int* __restrict__ esrc_p, int* __restrict__ dst_p,
                          int* __restrict__ cid_p){
  for (int e = blockIdx.x * blockDim.x + threadIdx.x; e < NE; e += gridDim.x * blockDim.x){
    const int d = edst[e];
    const int pos = atomicAdd(&head[d], 1);
    esrc_p[pos] = esrc[e];
    dst_p[pos] = d;
    cid_p[pos] = bfeat[e * 3 + 0] * 64 + bfeat[e * 3 + 1] * 8 + bfeat[e * 3 + 2];
  }
}

// ---------------- per-layer node precompute: prea/preb = hbf@W1a/b (f16) + zero msum ----------------
__global__ __launch_bounds__(256) void pre_k(
    const ushort* __restrict__ hbf, const ushort* __restrict__ W1p,
    __half* __restrict__ prea, __half* __restrict__ preb,
    uint* __restrict__ msum2)
{
  const int tid = threadIdx.x;
  const int n0 = blockIdx.x * 64;
  const int lane = tid & 63, wv = tid >> 6;
  const int lr = lane & 15, lg = lane >> 4;
  const int arow = n0 + wv * 16 + lr;
  // issue the critical-path fragment loads first
  bf16x8 a[4];
#pragma unroll
  for (int ks = 0; ks < 4; ++ks)
    a[ks] = *(const bf16x8*)(hbf + (size_t)arow * HD + ks * 32 + lg * 8);
  { // zero this block's msum2 rows (fire-and-forget stores)
    uint4* mz = (uint4*)(msum2 + (size_t)n0 * 64);
    const uint4 z = make_uint4(0u, 0u, 0u, 0u);
#pragma unroll
    for (int i = 0; i < 4; ++i) mz[tid + i * 256] = z;
  }
  const f32x4 zero = {0.f, 0.f, 0.f, 0.f};
  f32x4 acc[16];
#pragma unroll
  for (int i = 0; i < 16; ++i) acc[i] = zero;
#pragma unroll
  for (int ks = 0; ks < 4; ++ks){
#pragma unroll
    for (int ct = 0; ct < 16; ++ct){
      const int oct = ks * 4 + lg + ((ct >= 8) ? 16 : 0);
      const int ncol = (ct & 7) * 16 + lr;
      bf16x8 b = *(const bf16x8*)(W1p + ((size_t)oct * HD + ncol) * 8);
      acc[ct] = __builtin_amdgcn_mfma_f32_16x16x32_bf16(a[ks], b, acc[ct], 0, 0, 0);
    }
  }
#pragma unroll
  for (int ct = 0; ct < 16; ++ct){
    __half* dstp = (ct < 8) ? prea : preb;
    const int ncol = (ct & 7) * 16 + lr;
#pragma unroll
    for (int r = 0; r < 4; ++r){
      const int nrow = n0 + wv * 16 + lg * 4 + r;
      dstp[(size_t)nrow * HD + ncol] = __float2half_rn(acc[ct][r]);
    }
  }
}

// ---------------- per-layer bond-combo contribution: ecb = ebf@W1c + b1 (f16) ----------------
__global__ __launch_bounds__(256) void ew1c_k(
    const ushort* __restrict__ ebf, const ushort* __restrict__ W1p_all,
    const float* __restrict__ b1_all, __half* __restrict__ ecb_all)
{
  const int l = blockIdx.y;
  const ushort* W1p = W1p_all + (size_t)l * 384 * HD;
  const float* b1v = b1_all + l * HD;
  __half* ecb = ecb_all + (size_t)l * 512 * HD;
  const int tid = threadIdx.x;
  const int c0 = blockIdx.x * 64;
  const int lane = tid & 63, wv = tid >> 6;
  const int lr = lane & 15, lg = lane >> 4;
  const int arow = c0 + wv * 16 + lr;
  bf16x8 a[4];
#pragma unroll
  for (int ks = 0; ks < 4; ++ks)
    a[ks] = *(const bf16x8*)(ebf + (size_t)arow * HD + ks * 32 + lg * 8);
  const f32x4 zero = {0.f, 0.f, 0.f, 0.f};
  f32x4 acc[8];
#pragma unroll
  for (int i = 0; i < 8; ++i) acc[i] = zero;
#pragma unroll
  for (int ks = 0; ks < 4; ++ks){
#pragma unroll
    for (int ct = 0; ct < 8; ++ct){
      const int oct = ks * 4 + lg + 32;
      const int ncol = ct * 16 + lr;
      bf16x8 b = *(const bf16x8*)(W1p + ((size_t)oct * HD + ncol) * 8);
      acc[ct] = __builtin_amdgcn_mfma_f32_16x16x32_bf16(a[ks], b, acc[ct], 0, 0, 0);
    }
  }
#pragma unroll
  for (int ct = 0; ct < 8; ++ct){
    const int ncol = ct * 16 + lr;
    const float bias = b1v[ncol];
#pragma unroll
    for (int r = 0; r < 4; ++r){
      const int nrow = c0 + wv * 16 + lg * 4 + r;
      ecb[(size_t)nrow * HD + ncol] = __float2half_rn(acc[ct][r] + bias);
    }
  }
}

// ---------------- fused edge kernel: 128 edges/block, 2 tiles/wave sharing B ----------------
// issue-early: per ks-step, all 6 gather loads (both tiles) before any silu math
__device__ __forceinline__ void build_af2(
    const __half* __restrict__ prea, const __half* __restrict__ preb,
    const __half* __restrict__ ecb,
    int s0, int d0, int c0, int s1, int d1, int c1, int lg,
    f16x8* af0, f16x8* af1)
{
#pragma unroll
  for (int ks = 0; ks < 4; ++ks){
    const int off = ks * 32 + lg * 8;
    union { uint4 q; __half2 h[4]; f16x8 v; } ua0, ub0, uc0, uo0, ua1, ub1, uc1, uo1;
    ua0.q = *(const uint4*)(prea + (size_t)s0 * HD + off);
    ub0.q = *(const uint4*)(preb + (size_t)d0 * HD + off);
    uc0.q = *(const uint4*)(ecb + (size_t)c0 * HD + off);
    ua1.q = *(const uint4*)(prea + (size_t)s1 * HD + off);
    ub1.q = *(const uint4*)(preb + (size_t)d1 * HD + off);
    uc1.q = *(const uint4*)(ecb + (size_t)c1 * HD + off);
#pragma unroll
    for (int j = 0; j < 4; ++j){
      uo0.h[j] = silu_h2(__hadd2(__hadd2(ua0.h[j], ub0.h[j]), uc0.h[j]));
      uo1.h[j] = silu_h2(__hadd2(__hadd2(ua1.h[j], ub1.h[j]), uc1.h[j]));
    }
    af0[ks] = uo0.v;
    af1[ks] = uo1.v;
  }
}

__device__ __forceinline__ void edge_epilogue(
    f32x4* acc, int lr, int lg, int rowbase,
    const float* b2l, const float* b2h, const __half2* gwh, float gbias,
    uint* Ms)
{
  __half2 mh[4][4];
#pragma unroll
  for (int ct = 0; ct < 4; ++ct){
#pragma unroll
    for (int r = 0; r < 4; ++r)
      mh[ct][r] = silu_h2(pkrtz(acc[ct][r] + b2l[ct], acc[ct + 4][r] + b2h[ct]));
  }
#pragma unroll
  for (int r = 0; r < 4; ++r){
    float sgs = 0.f;
#pragma unroll
    for (int ct = 0; ct < 4; ++ct){
      H2U a, b; a.h = mh[ct][r]; b.h = gwh[ct];
      sgs = __builtin_amdgcn_fdot2(a.v, b.v, sgs, false);
    }
    sgs += __shfl_xor(sgs, 1); sgs += __shfl_xor(sgs, 2);
    sgs += __shfl_xor(sgs, 4); sgs += __shfl_xor(sgs, 8);
    const __half2 gh = __float2half2_rn(sigmf(sgs + gbias));
#pragma unroll
    for (int ct = 0; ct < 4; ++ct) mh[ct][r] = __hmul2(mh[ct][r], gh);
  }
#pragma unroll
  for (int ct = 0; ct < 4; ++ct){
    const int ui = ct * 16 + lr;
#pragma unroll
    for (int r = 0; r < 4; ++r){
      const int lrow = rowbase + lg * 4 + r;
      H2U w; w.h = mh[ct][r];
      *(uint*)((char*)Ms + lrow * 256 + (((uint)(ui * 4)) ^ ((uint)((lrow & 7) << 4)))) = w.u;
    }
  }
}

__global__ __launch_bounds__(256, 4) void msg2_kernel(
    const __half* __restrict__ prea, const __half* __restrict__ preb,
    const __half* __restrict__ ecb,
    const int* __restrict__ esrc_p, const int* __restrict__ dst_p,
    const int* __restrict__ cid_p,
    const __half* __restrict__ W2p, const float* __restrict__ b2v,
    const float* __restrict__ gw, const float* __restrict__ gb,
    __half2* __restrict__ msum2)
{
  __shared__ uint Ms[128 * 64]; // parked m pairs for 128 edges; row stride 256B, swizzled
  __shared__ int dsh[128];
  const int tid = threadIdx.x;
  // chunked XCD swizzle (bijective: NBLK2 % 8 == 0)
  const int bid = (int)blockIdx.x;
  const int bsw = (bid & 7) * (NBLK2 >> 3) + (bid >> 3);
  const int e0 = bsw * 128;
  if (tid < 128) dsh[tid] = dst_p[e0 + tid];

  const int lane = tid & 63;
  const int wv = tid >> 6;
  const int lr = lane & 15, lg = lane >> 4;
  const int row0 = e0 + wv * 16 + lr;       // tile 0 edge row
  const int row1 = row0 + 64;               // tile 1 edge row
  const int s0 = esrc_p[row0], d0 = dst_p[row0], c0 = cid_p[row0];
  const int s1 = esrc_p[row1], d1 = dst_p[row1], c1 = cid_p[row1];

  f16x8 af0[4], af1[4];
  build_af2(prea, preb, ecb, s0, d0, c0, s1, d1, c1, lg, af0, af1);

  // GEMM2 for both tiles, one B-load per (ks,ct)
  const f32x4 zero = {0.f, 0.f, 0.f, 0.f};
  f32x4 acc0[8], acc1[8];
#pragma unroll
  for (int i = 0; i < 8; ++i){ acc0[i] = zero; acc1[i] = zero; }
#pragma unroll
  for (int ks = 0; ks < 4; ++ks){
    const __half* wb = W2p + ((size_t)(ks * 4 + lg) * HD + lr) * 8;
#pragma unroll
    for (int ct = 0; ct < 8; ++ct){
      f16x8 b = *(const f16x8*)(wb + ct * 16 * 8);
      acc0[ct] = __builtin_amdgcn_mfma_f32_16x16x32_f16(af0[ks], b, acc0[ct], 0, 0, 0);
      acc1[ct] = __builtin_amdgcn_mfma_f32_16x16x32_f16(af1[ks], b, acc1[ct], 0, 0, 0);
    }
  }

  float b2l[4], b2h[4];
  __half2 gwh[4];
#pragma unroll
  for (int ct = 0; ct < 4; ++ct){
    b2l[ct] = b2v[ct * 16 + lr];
    b2h[ct] = b2v[ct * 16 + lr + 64];
    gwh[ct] = pkrtz(gw[ct * 16 + lr], gw[ct * 16 + lr + 64]);
  }
  const float gbias = gb[0];
  edge_epilogue(acc0, lr, lg, wv * 16, b2l, b2h, gwh, gbias, Ms);
  edge_epilogue(acc1, lr, lg, 64 + wv * 16, b2l, b2h, gwh, gbias, Ms);
  __syncthreads();

  // segmented reduction: 64 col-pairs x 4 row-segments of 32; one packed-f16 atomic per run
  {
    const int cp = tid & 63;
    const int seg = tid >> 6;
    const int r0 = seg * 32, r1 = r0 + 32;
    float rl = 0.f, rh = 0.f;
    int cur = dsh[r0];
    for (int r = r0; r < r1; ++r){
      const int dd = dsh[r];
      if (dd != cur){
        unsafeAtomicAdd(&msum2[(size_t)cur * 64 + cp], pkrtz(rl, rh));
        rl = 0.f; rh = 0.f; cur = dd;
      }
      H2U w;
      w.u = *(const uint*)((const char*)Ms + r * 256 +
                           (((uint)(cp * 4)) ^ ((uint)((r & 7) << 4))));
      rl += __low2float(w.h); rh += __high2float(w.h);
    }
    unsafeAtomicAdd(&msum2[(size_t)cur * 64 + cp], pkrtz(rl, rh));
  }
}

// ---------------- fused node MLP (64 nodes/block, issue-early stage) ----------------
// MODE 0: A = bf16(h + msum); out = silu(A@W1+b1)@W2 + b2 + h -> h, hbf
// MODE 1: A = bf16(h);        out = silu(A@W1+b1)@W2 + b2     -> outp
template <int MODE>
__global__ __launch_bounds__(256) void node_mlp(
    const float* hin, const uint* __restrict__ msum2,
    const ushort* __restrict__ W1p, const ushort* __restrict__ W2p,
    const float* __restrict__ b1v, const float* __restrict__ b2v,
    float* outp, ushort* __restrict__ hbf)
{
  __shared__ ushort At[64 * 128];
  __shared__ ushort Tt[64 * 128];
  const int tid = threadIdx.x;
  const int n0 = blockIdx.x * 64;

  { // stage: 4 threads per node, 32 cols each; issue ALL loads before any math
    const int nl = tid >> 2, part = tid & 3;
    const int node = n0 + nl;
    const float4* hp = (const float4*)(hin + (size_t)node * HD + part * 32);
    const uint* mp = (MODE == 0) ? (msum2 + (size_t)node * 64) : nullptr;
    const bool hiHalf = (MODE == 0) && (part >= 2);
    char* rowp = (char*)At + nl * 256;
    const uint sw = (uint)((nl & 7) << 4);
    float4 hx[8];
    uint4 mu[8];
#pragma unroll
    for (int j = 0; j < 8; ++j) hx[j] = hp[j];
    if (MODE == 0){
#pragma unroll
      for (int j = 0; j < 4; ++j){
        const int cp0 = (part & 1) * 32 + j * 8;
        mu[j * 2 + 0] = *(const uint4*)(mp + cp0);
        mu[j * 2 + 1] = *(const uint4*)(mp + cp0 + 4);
      }
    }
#pragma unroll
    for (int j = 0; j < 4; ++j){
      float4 x0 = hx[j * 2 + 0], x1 = hx[j * 2 + 1];
      if (MODE == 0){
        uint4 ma = mu[j * 2 + 0];
        uint4 mb = mu[j * 2 + 1];
        H2U w0, w1, w2, w3, w4, w5, w6, w7;
        w0.u = ma.x; w1.u = ma.y; w2.u = ma.z; w3.u = ma.w;
        w4.u = mb.x; w5.u = mb.y; w6.u = mb.z; w7.u = mb.w;
        if (hiHalf){
          x0.x += __high2float(w0.h); x0.y += __high2float(w1.h);
          x0.z += __high2float(w2.h); x0.w += __high2float(w3.h);
          x1.x += __high2float(w4.h); x1.y += __high2float(w5.h);
          x1.z += __high2float(w6.h); x1.w += __high2float(w7.h);
        } else {
          x0.x += __low2float(w0.h); x0.y += __low2float(w1.h);
          x0.z += __low2float(w2.h); x0.w += __low2float(w3.h);
          x1.x += __low2float(w4.h); x1.y += __low2float(w5.h);
          x1.z += __low2float(w6.h); x1.w += __low2float(w7.h);
        }
      }
      uint4 o;
      o.x = packbf2(x0.x, x0.y); o.y = packbf2(x0.z, x0.w);
      o.z = packbf2(x1.x, x1.y); o.w = packbf2(x1.z, x1.w);
      uint cb = (uint)(part * 64 + j * 16);
      *(uint4*)(rowp + (cb ^ sw)) = o;
    }
  }
  __syncthreads();

  const int lane = tid & 63;
  const int wv = tid >> 6;
  const int lr = lane & 15, lg = lane >> 4;
  const int rowbase = wv * 16;
  const f32x4 zero = {0.f, 0.f, 0.f, 0.f};
  const int arow = rowbase + lr;
  const char* arp = (const char*)At + arow * 256;
  const uint asw = (uint)((arow & 7) << 4);

  f32x4 acc[8];
#pragma unroll
  for (int i = 0; i < 8; ++i) acc[i] = zero;
#pragma unroll
  for (int ks = 0; ks < 4; ++ks){
    uint cb = (uint)(ks * 64 + lg * 16);
    bf16x8 a = *(const bf16x8*)(arp + (cb ^ asw));
    const ushort* wbase = W1p + ((size_t)(ks * 4 + lg) * 128 + lr) * 8;
#pragma unroll
    for (int ct = 0; ct < 8; ++ct){
      bf16x8 b = *(const bf16x8*)(wbase + ct * 16 * 8);
      acc[ct] = __builtin_amdgcn_mfma_f32_16x16x32_bf16(a, b, acc[ct], 0, 0, 0);
    }
  }
#pragma unroll
  for (int ct = 0; ct < 8; ++ct){
    const int col = ct * 16 + lr;
    const float bias = b1v[col];
#pragma unroll
    for (int r = 0; r < 4; ++r){
      const int row = rowbase + lg * 4 + r;
      float v = siluf(acc[ct][r] + bias);
      *(ushort*)((char*)Tt + row * 256 + (((uint)(col * 2)) ^ ((uint)(row & 7) << 4))) = f2bf(v);
    }
  }
  __syncthreads();

  f32x4 acc2[8];
#pragma unroll
  for (int i = 0; i < 8; ++i) acc2[i] = zero;
  {
    const char* trp = (const char*)Tt + arow * 256;
#pragma unroll
    for (int ks = 0; ks < 4; ++ks){
      uint cb = (uint)(ks * 64 + lg * 16);
      bf16x8 a = *(const bf16x8*)(trp + (cb ^ asw));
      const ushort* wbase = W2p + ((size_t)(ks * 4 + lg) * 128 + lr) * 8;
#pragma unroll
      for (int ct = 0; ct < 8; ++ct){
        bf16x8 b = *(const bf16x8*)(wbase + ct * 16 * 8);
        acc2[ct] = __builtin_amdgcn_mfma_f32_16x16x32_bf16(a, b, acc2[ct], 0, 0, 0);
      }
    }
  }
#pragma unroll
  for (int ct = 0; ct < 8; ++ct){
    const int col = ct * 16 + lr;
    const float bias = b2v[col];
#pragma unroll
    for (int r = 0; r < 4; ++r){
      const int node = n0 + rowbase + lg * 4 + r;
      float v = acc2[ct][r] + bias;
      if (MODE == 0) v += hin[(size_t)node * HD + col];
      outp[(size_t)node * HD + col] = v;
      if (MODE == 0) hbf[(size_t)node * HD + col] = f2bf(v);
    }
  }
}

// ---------------- fused per-graph readout + final MLP ----------------
__global__ __launch_bounds__(128) void readout_final(
    const float* __restrict__ hout, const int* __restrict__ n2g,
    const float* __restrict__ W1, const float* __restrict__ b1,
    const float* __restrict__ W2, const float* __restrict__ b2,
    float* __restrict__ out){
  __shared__ float rsh[384];
  __shared__ float hr[128];
  const int g = blockIdx.x;
  const int c = threadIdx.x; // 128
  int lo, hi;
  { int a = 0, b = NN; while (a < b){ int mid = (a + b) >> 1; if (n2g[mid] < g) a = mid + 1; else b = mid; } lo = a; }
  { int a = lo, b = NN; while (a < b){ int mid = (a + b) >> 1; if (n2g[mid] < g + 1) a = mid + 1; else b = mid; } hi = a; }
  float s = 0.f, mx = -3.4e38f;
  for (int n = lo; n < hi; ++n){
    float v = hout[(size_t)n * HD + c];
    s += v; mx = fmaxf(mx, v);
  }
  const int cnt = hi - lo;
  float mean = (cnt > 0) ? s / (float)cnt : 0.f;
  if (cnt == 0){ s = 0.f; mx = 0.f; }
  rsh[c] = s; rsh[128 + c] = mean; rsh[256 + c] = mx;
  __syncthreads();
  float acc = b1[c];
#pragma unroll 4
  for (int j = 0; j < 384; ++j) acc += rsh[j] * W1[j * 128 + c];
  hr[c] = fmaxf(acc, 0.f);
  __syncthreads();
  if (c < TD){
    float o = b2[c];
#pragma unroll 4
    for (int j = 0; j < 128; ++j) o += hr[j] * W2[j * TD + c];
    out[(size_t)g * TD + c] = o;
  }
}

extern "C" void kernel_launch(void* const* d_in, const int* in_sizes, int n_in,
                              void* d_out, int out_size, void* d_ws, size_t ws_size,
                              hipStream_t stream)
{
  const int*   atom_feat  = (const int*)  d_in[0];
  const int*   bond_feat  = (const int*)  d_in[1];
  const int*   edge_src   = (const int*)  d_in[2];
  const int*   edge_dst   = (const int*)  d_in[3];
  const int*   node2graph = (const int*)  d_in[4];
  const float* atom_emb   = (const float*)d_in[5];
  const float* bond_emb   = (const float*)d_in[6];
  const float* msg_W1     = (const float*)d_in[7];
  const float* msg_b1     = (const float*)d_in[8];
  const float* msg_W2     = (const float*)d_in[9];
  const float* msg_b2     = (const float*)d_in[10];
  const float* gate_W     = (const float*)d_in[11];
  const float* gate_b     = (const float*)d_in[12];
  const float* upd_W1     = (const float*)d_in[13];
  const float* upd_b1     = (const float*)d_in[14];
  const float* upd_W2     = (const float*)d_in[15];
  const float* upd_b2     = (const float*)d_in[16];
  const float* out_W1     = (const float*)d_in[17];
  const float* out_b1     = (const float*)d_in[18];
  const float* out_W2     = (const float*)d_in[19];
  const float* out_b2     = (const float*)d_in[20];
  const float* ro_W1      = (const float*)d_in[21];
  const float* ro_b1      = (const float*)d_in[22];
  const float* ro_W2      = (const float*)d_in[23];
  const float* ro_b2      = (const float*)d_in[24];
  (void)in_sizes; (void)n_in; (void)out_size; (void)ws_size;

  char* ws = (char*)d_ws;
  size_t off = 0;
  auto alloc = [&](size_t bytes) -> char* {
    char* p = ws + off;
    off = (off + bytes + 255) & ~(size_t)255;
    return p;
  };
  float*   h      = (float*)  alloc((size_t)NN * HD * 4);
  float*   hout   = (float*)  alloc((size_t)NN * HD * 4);
  ushort*  hbf    = (ushort*) alloc((size_t)NN * HD * 2);
  __half2* msum2  = (__half2*)alloc((size_t)NN * 64 * 4);
  ushort*  msgW1p = (ushort*) alloc((size_t)DEPTH * 384 * HD * 2);
  ushort*  msgW2p = (ushort*) alloc((size_t)DEPTH * HD * HD * 2); // f16
  ushort*  updW1p = (ushort*) alloc((size_t)DEPTH * HD * HD * 2);
  ushort*  updW2p = (ushort*) alloc((size_t)DEPTH * HD * HD * 2);
  ushort*  outW1p = (ushort*) alloc((size_t)HD * HD * 2);
  ushort*  outW2p = (ushort*) alloc((size_t)HD * HD * 2);
  ushort*  ebf    = (ushort*) alloc((size_t)512 * HD * 2);
  __half*  ecb    = (__half*) alloc((size_t)DEPTH * 512 * HD * 2);
  __half*  prea   = (__half*) alloc((size_t)NN * HD * 2);
  __half*  preb   = (__half*) alloc((size_t)NN * HD * 2);
  int*     deg    = (int*)    alloc((size_t)NN * 4);
  int*     head   = (int*)    alloc((size_t)NN * 4);
  int*     esrc_p = (int*)    alloc((size_t)NE * 4);
  int*     dst_p  = (int*)    alloc((size_t)NE * 4);
  int*     cid_p  = (int*)    alloc((size_t)NE * 4);

  pack6<<<dim3(48, 6), 256, 0, stream>>>(msg_W1, msg_W2, upd_W1, upd_W2, out_W1, out_W2,
                                         msgW1p, msgW2p, updW1p, updW2p, outW1p, outW2p);
  atom_encode<<<NN, HD, 0, stream>>>(atom_feat, atom_emb, h, hbf);
  ebf_k<<<512, HD, 0, stream>>>(bond_emb, ebf);
  ew1c_k<<<dim3(8, DEPTH), 256, 0, stream>>>(ebf, msgW1p, msg_b1, ecb);

  // counting sort of edges by dst
  zero_i<<<160, 256, 0, stream>>>(deg, NN);
  hist_k<<<640, 256, 0, stream>>>(edge_dst, deg);
  scan_head<<<1, 1024, 0, stream>>>(deg, head);
  scatter_k<<<640, 256, 0, stream>>>(edge_src, edge_dst, bond_feat, head,
                                     esrc_p, dst_p, cid_p);

  for (int l = 0; l < DEPTH; ++l){
    pre_k<<<NN / 64, 256, 0, stream>>>(hbf, msgW1p + (size_t)l * 384 * HD, prea, preb,
                                       (uint*)msum2);
    msg2_kernel<<<NBLK2, 256, 0, stream>>>(
        prea, preb, ecb + (size_t)l * 512 * HD,
        esrc_p, dst_p, cid_p,
        (const __half*)msgW2p + (size_t)l * HD * HD,
        msg_b2 + l * HD, gate_W + l * HD, gate_b + l, msum2);
    node_mlp<0><<<NN / 64, 256, 0, stream>>>(
        h, (const uint*)msum2,
        updW1p + (size_t)l * HD * HD, updW2p + (size_t)l * HD * HD,
        upd_b1 + l * HD, upd_b2 + l * HD, h, hbf);
  }
  node_mlp<1><<<NN / 64, 256, 0, stream>>>(
      h, nullptr, outW1p, outW2p, out_b1, out_b2, hout, nullptr);
  readout_final<<<NG, 128, 0, stream>>>(hout, node2graph, ro_W1, ro_b1, ro_W2, ro_b2,
                                        (float*)d_out);
}